// Round 16
// baseline (295.627 us; speedup 1.0000x reference)
//
#include <hip/hip_runtime.h>
#include <hip/hip_bf16.h>
#include <math.h>

// ChebyNet: 2-layer ChebConv (K=4), N=100000, E=1600000, F 32->16->10, log_softmax.
//
// R16 = R15 + tail fusion: the 3rd prop of each layer is fused with its
// combine (prop_combine1 / prop_combine2). u3/us3 are never written to global
// (-19MB traffic); the fused combine uses the fp32 chunk directly. Per-node
// lane groups (4 resp. 2) compute partial accs, butterfly-reduce via
// __shfl_xor (groups wave-aligned), lanes write hb/uh chunks resp. 5-float
// output halves. 9 dispatches (was 11).
// Rest = R15: U-space recurrence, src-quartile-ordered edge lists, bf16
// tables (64B rows L1, 32B rows L2), fixed-capacity bucket CSR build with
// fused u0 conversion, 8-edges-in-flight props, __launch_bounds__ everywhere.

#define BLK 256
#define BLKP 512
#define NBUCK_MAX 256   // buckets = ceil(N/512); requires N <= 131072
#define CHUNK 8192      // edges per binned_scatter block
#define CAPB 16384      // fixed capacity per bucket region in tmp/psrc
#define PLACE_CAP 10240 // LDS staging capacity in bucket_place (avg bucket 8192)

// ---------- bf16 helpers (storage-only quantization) ----------
__device__ inline unsigned short f32_to_bf16_rne(float f) {
    unsigned int u = __float_as_uint(f);
    unsigned int rounding = 0x7FFFu + ((u >> 16) & 1u);
    return (unsigned short)((u + rounding) >> 16);
}
__device__ inline unsigned int pack_bf16x2(float a, float b) {
    return (unsigned int)f32_to_bf16_rne(a) | ((unsigned int)f32_to_bf16_rne(b) << 16);
}
__device__ inline void unpack8(const uint4 u, float* f) {
    const unsigned int* p = &u.x;
#pragma unroll
    for (int j = 0; j < 4; j++) {
        unsigned int w = p[j];
        f[2 * j]     = __uint_as_float(w << 16);
        f[2 * j + 1] = __uint_as_float(w & 0xFFFF0000u);
    }
}
__device__ inline void add8(const uint4 u, float* acc) {
    const unsigned int* p = &u.x;
#pragma unroll
    for (int j = 0; j < 4; j++) {
        unsigned int w = p[j];
        acc[2 * j]     += __uint_as_float(w << 16);
        acc[2 * j + 1] += __uint_as_float(w & 0xFFFF0000u);
    }
}
__device__ inline uint4 pack8(const float* r) {
    uint4 o;
    o.x = pack_bf16x2(r[0], r[1]);
    o.y = pack_bf16x2(r[2], r[3]);
    o.z = pack_bf16x2(r[4], r[5]);
    o.w = pack_bf16x2(r[6], r[7]);
    return o;
}

// ---------- CSR build (fixed-capacity buckets) ----------
__global__ __launch_bounds__(BLK)
void binned_scatter_kernel(const int* __restrict__ src, const int* __restrict__ dst,
                           int* __restrict__ bfill, int* __restrict__ tmp,
                           int E, int nbuck) {
    __shared__ int cnt[NBUCK_MAX];
    __shared__ int lofs[NBUCK_MAX + 1];
    __shared__ int pos[NBUCK_MAX];
    __shared__ int gbase[NBUCK_MAX];
    __shared__ int stage[CHUNK];
    __shared__ unsigned char bkt[CHUNK];

    int tid = threadIdx.x;
    int e0 = blockIdx.x * CHUNK;
    int nE = min(CHUNK, E - e0);

    for (int b = tid; b < nbuck; b += BLK) { cnt[b] = 0; pos[b] = 0; }
    __syncthreads();

    for (int i = tid; i < nE; i += BLK) {
        int d = dst[e0 + i];
        atomicAdd(&cnt[d >> 9], 1);
    }
    __syncthreads();

    {
        int v = (tid < nbuck) ? cnt[tid] : 0;
        lofs[tid] = v;
        __syncthreads();
        for (int off = 1; off < BLK; off <<= 1) {
            int t = (tid >= off) ? lofs[tid - off] : 0;
            __syncthreads();
            lofs[tid] += t;
            __syncthreads();
        }
        int incl = lofs[tid];
        __syncthreads();
        lofs[tid] = incl - v;
        if (tid == 0) lofs[nbuck] = nE;
        if (tid < nbuck && v > 0)
            gbase[tid] = tid * CAPB + atomicAdd(&bfill[tid], v);
    }
    __syncthreads();

    for (int i = tid; i < nE; i += BLK) {
        int s = src[e0 + i];
        int d = dst[e0 + i];
        int b = d >> 9;
        int slot = lofs[b] + atomicAdd(&pos[b], 1);
        stage[slot] = (s << 9) | (d & 511);
        bkt[slot] = (unsigned char)b;
    }
    __syncthreads();

    for (int i = tid; i < nE; i += BLK) {
        int b = bkt[i];
        tmp[gbase[b] + (i - lofs[b])] = stage[i];
    }
}

// Phase 2: per-bucket degree count/scan -> rowbeg/rowend/dis/d2/inv + fused u0;
// rank+stage+flush psrc with each node's edges ordered by src quartile.
__global__ __launch_bounds__(BLKP)
void bucket_place_kernel(const int* __restrict__ bfill, const int* __restrict__ tmp,
                         int* __restrict__ psrc, int* __restrict__ rowbeg,
                         int* __restrict__ rowend, float* __restrict__ dis,
                         float* __restrict__ d2, float* __restrict__ inv,
                         const float* __restrict__ x, uint4* __restrict__ u0, int N) {
    __shared__ int cnt4[512 * 4];
    __shared__ int ofs[512];
    __shared__ int fill4[512 * 4];
    __shared__ int stage[PLACE_CAP];

    int b = blockIdx.x;
    int tid = threadIdx.x;
    int n0 = b << 9;
    int nn = min(512, N - n0);
    int S = b * CAPB;
    int tot = bfill[b];

    int t1 = N >> 2, t2 = N >> 1, t3 = t2 + t1;

    for (int i = tid; i < 512 * 4; i += BLKP) { cnt4[i] = 0; fill4[i] = 0; }
    __syncthreads();

    for (int i = tid; i < tot; i += BLKP) {
        int rec = tmp[S + i];
        int nl = rec & 511;
        int s = rec >> 9;
        int q = (s >= t2) ? ((s >= t3) ? 3 : 2) : ((s >= t1) ? 1 : 0);
        atomicAdd(&cnt4[nl * 4 + q], 1);
    }
    __syncthreads();

    int c0 = cnt4[tid * 4 + 0], c1 = cnt4[tid * 4 + 1];
    int c2 = cnt4[tid * 4 + 2], c3 = cnt4[tid * 4 + 3];
    int v = c0 + c1 + c2 + c3;
    cnt4[tid * 4 + 0] = 0;
    cnt4[tid * 4 + 1] = c0;
    cnt4[tid * 4 + 2] = c0 + c1;
    cnt4[tid * 4 + 3] = c0 + c1 + c2;
    ofs[tid] = v;
    __syncthreads();
    for (int off = 1; off < 512; off <<= 1) {
        int t = (tid >= off) ? ofs[tid - off] : 0;
        __syncthreads();
        ofs[tid] += t;
        __syncthreads();
    }
    int excl = ofs[tid] - v;
    __syncthreads();
    ofs[tid] = excl;
    float dn = (v > 0) ? rsqrtf((float)v) : 0.0f;
    if (tid < nn) {
        int n = n0 + tid;
        rowbeg[n] = S + excl;
        rowend[n] = S + excl + v;
        float fv = (float)v;
        dis[n] = dn;
        d2[n]  = (v > 0) ? 1.0f / fv : 0.0f;
        inv[n] = (v > 0) ? sqrtf(fv) : 0.0f;
        const float4* xr = reinterpret_cast<const float4*>(x + (size_t)n * 32);
#pragma unroll
        for (int c = 0; c < 4; c++) {
            float4 a = xr[c * 2], bb = xr[c * 2 + 1];
            float r[8] = {dn * a.x, dn * a.y, dn * a.z, dn * a.w,
                          dn * bb.x, dn * bb.y, dn * bb.z, dn * bb.w};
            u0[(size_t)n * 4 + c] = pack8(r);
        }
    }
    __syncthreads();

    if (tot <= PLACE_CAP) {
        for (int i = tid; i < tot; i += BLKP) {
            int rec = tmp[S + i];
            int nl = rec & 511;
            int s = rec >> 9;
            int q = (s >= t2) ? ((s >= t3) ? 3 : 2) : ((s >= t1) ? 1 : 0);
            int slot = ofs[nl] + cnt4[nl * 4 + q] + atomicAdd(&fill4[nl * 4 + q], 1);
            stage[slot] = s;
        }
        __syncthreads();
        for (int i = tid; i < tot; i += BLKP) psrc[S + i] = stage[i];
    } else {
        for (int i = tid; i < tot; i += BLKP) {
            int rec = tmp[S + i];
            int nl = rec & 511;
            int s = rec >> 9;
            int q = (s >= t2) ? ((s >= t3) ? 3 : 2) : ((s >= t1) ? 1 : 0);
            int slot = S + ofs[nl] + cnt4[nl * 4 + q] + atomicAdd(&fill4[nl * 4 + q], 1);
            psrc[slot] = s;
        }
    }
}

// ---------- U-space props: pure gather-sum, 8 edges in flight ----------
template <int C, bool HAVE_PREV>
__global__ __launch_bounds__(BLK)
void prop_u_kernel(const int* __restrict__ rowbeg, const int* __restrict__ rowend,
                   const int* __restrict__ psrc, const float* __restrict__ d2,
                   const uint4* __restrict__ vb, const uint4* __restrict__ prevb,
                   uint4* __restrict__ outb, float scale, int N) {
    int t = blockIdx.x * blockDim.x + threadIdx.x;
    int n = t / C;
    int c = t % C;
    if (n >= N) return;
    int beg = rowbeg[n];
    int end = rowend[n];
    float acc[8];
#pragma unroll
    for (int j = 0; j < 8; j++) acc[j] = 0.f;
    int i = beg;
    for (; i + 7 < end; i += 8) {
        int s0 = psrc[i],     s1 = psrc[i + 1], s2 = psrc[i + 2], s3 = psrc[i + 3];
        int s4 = psrc[i + 4], s5 = psrc[i + 5], s6 = psrc[i + 6], s7 = psrc[i + 7];
        uint4 a0 = vb[(size_t)s0 * C + c];
        uint4 a1 = vb[(size_t)s1 * C + c];
        uint4 a2 = vb[(size_t)s2 * C + c];
        uint4 a3 = vb[(size_t)s3 * C + c];
        uint4 a4 = vb[(size_t)s4 * C + c];
        uint4 a5 = vb[(size_t)s5 * C + c];
        uint4 a6 = vb[(size_t)s6 * C + c];
        uint4 a7 = vb[(size_t)s7 * C + c];
        add8(a0, acc); add8(a1, acc); add8(a2, acc); add8(a3, acc);
        add8(a4, acc); add8(a5, acc); add8(a6, acc); add8(a7, acc);
    }
    for (; i + 3 < end; i += 4) {
        int s0 = psrc[i], s1 = psrc[i + 1], s2 = psrc[i + 2], s3 = psrc[i + 3];
        uint4 a0 = vb[(size_t)s0 * C + c];
        uint4 a1 = vb[(size_t)s1 * C + c];
        uint4 a2 = vb[(size_t)s2 * C + c];
        uint4 a3 = vb[(size_t)s3 * C + c];
        add8(a0, acc); add8(a1, acc); add8(a2, acc); add8(a3, acc);
    }
    for (; i < end; i++) {
        uint4 a0 = vb[(size_t)psrc[i] * C + c];
        add8(a0, acc);
    }
    float f = -scale * d2[n];
    float r[8];
    if (HAVE_PREV) {
        float p[8];
        unpack8(prevb[(size_t)n * C + c], p);
#pragma unroll
        for (int j = 0; j < 8; j++) r[j] = f * acc[j] - p[j];
    } else {
#pragma unroll
        for (int j = 0; j < 8; j++) r[j] = f * acc[j];
    }
    outb[(size_t)n * C + c] = pack8(r);
}

// ---------- Fused: u3-prop + combine1 (u3 never materialized) ----------
// 4 lanes/node; lane c: gather-sum u2 rows (chunk c), u3c = -2*d2*acc - u1c;
// partial acc16 over this lane's 8 input feats x 4 k-terms; butterfly-reduce;
// lanes write hb (0,1) and uh (2,3) chunks.
__global__ __launch_bounds__(BLK)
void prop_combine1_kernel(const int* __restrict__ rowbeg, const int* __restrict__ rowend,
                          const int* __restrict__ psrc, const float* __restrict__ d2,
                          const uint4* __restrict__ u2t, const uint4* __restrict__ u1t,
                          const float* __restrict__ x, const float* __restrict__ inv,
                          const float* __restrict__ dis, const float* __restrict__ W1,
                          const float* __restrict__ b1, uint4* __restrict__ hb,
                          uint4* __restrict__ uh, int N) {
    __shared__ float sW[4 * 32 * 16];
    __shared__ float sb[16];
    for (int i = threadIdx.x; i < 4 * 32 * 16; i += blockDim.x) sW[i] = W1[i];
    if (threadIdx.x < 16) sb[threadIdx.x] = b1[threadIdx.x];
    __syncthreads();
    int t = blockIdx.x * blockDim.x + threadIdx.x;
    int n = t >> 2;
    int c = t & 3;
    if (n >= N) return;
    // --- prop: u3 chunk ---
    int beg = rowbeg[n];
    int end = rowend[n];
    float acc[8];
#pragma unroll
    for (int j = 0; j < 8; j++) acc[j] = 0.f;
    int i = beg;
    for (; i + 7 < end; i += 8) {
        int s0 = psrc[i],     s1 = psrc[i + 1], s2 = psrc[i + 2], s3 = psrc[i + 3];
        int s4 = psrc[i + 4], s5 = psrc[i + 5], s6 = psrc[i + 6], s7 = psrc[i + 7];
        uint4 a0 = u2t[(size_t)s0 * 4 + c];
        uint4 a1 = u2t[(size_t)s1 * 4 + c];
        uint4 a2 = u2t[(size_t)s2 * 4 + c];
        uint4 a3 = u2t[(size_t)s3 * 4 + c];
        uint4 a4 = u2t[(size_t)s4 * 4 + c];
        uint4 a5 = u2t[(size_t)s5 * 4 + c];
        uint4 a6 = u2t[(size_t)s6 * 4 + c];
        uint4 a7 = u2t[(size_t)s7 * 4 + c];
        add8(a0, acc); add8(a1, acc); add8(a2, acc); add8(a3, acc);
        add8(a4, acc); add8(a5, acc); add8(a6, acc); add8(a7, acc);
    }
    for (; i < end; i++) add8(u2t[(size_t)psrc[i] * 4 + c], acc);
    float f = -2.0f * d2[n];
    float p1[8], p2[8], r[8];
    unpack8(u1t[(size_t)n * 4 + c], p1);
    unpack8(u2t[(size_t)n * 4 + c], p2);
#pragma unroll
    for (int j = 0; j < 8; j++) r[j] = f * acc[j] - p1[j];   // u3 chunk, fp32
    // --- combine1 partials over this lane's 8 input features ---
    float a16[16];
#pragma unroll
    for (int o = 0; o < 16; o++) a16[o] = (c == 0) ? sb[o] : 0.0f;
    float iv = inv[n];
    float xv[8];
    {
        const float4* xr = reinterpret_cast<const float4*>(x + (size_t)n * 32 + c * 8);
        float4 a = xr[0], bb = xr[1];
        xv[0] = a.x; xv[1] = a.y; xv[2] = a.z; xv[3] = a.w;
        xv[4] = bb.x; xv[5] = bb.y; xv[6] = bb.z; xv[7] = bb.w;
    }
    const float* W0 = sW + (c * 8) * 16;
#pragma unroll
    for (int j = 0; j < 8; j++) {
        float w0 = xv[j];
        float w1 = p1[j] * iv;
        float w2 = p2[j] * iv;
        float w3 = r[j] * iv;
        const float* Wj = W0 + j * 16;
#pragma unroll
        for (int o = 0; o < 16; o++)
            a16[o] += w0 * Wj[o] + w1 * Wj[512 + o] + w2 * Wj[1024 + o] + w3 * Wj[1536 + o];
    }
    if (iv == 0.0f) {  // deg-0 (rare): Tx2 = -x; Tx1 = Tx3 = 0 already
#pragma unroll
        for (int j = 0; j < 8; j++) {
            const float* Wj = W0 + j * 16 + 1024;
#pragma unroll
            for (int o = 0; o < 16; o++) a16[o] -= xv[j] * Wj[o];
        }
    }
    // --- butterfly reduce across the 4 lanes of this node ---
#pragma unroll
    for (int m = 1; m <= 2; m <<= 1) {
#pragma unroll
        for (int o = 0; o < 16; o++) a16[o] += __shfl_xor(a16[o], m);
    }
    // --- epilogue: lanes 0,1 -> hb chunks; lanes 2,3 -> uh chunks ---
    float dn = dis[n];
    int half = c & 1;
    float w8[8];
#pragma unroll
    for (int j = 0; j < 8; j++) {
        float v = fmaxf(a16[half * 8 + j], 0.0f);
        w8[j] = (c < 2) ? v : dn * v;
    }
    if (c < 2) hb[(size_t)n * 2 + half] = pack8(w8);
    else       uh[(size_t)n * 2 + half] = pack8(w8);
}

// ---------- Fused: us3-prop + combine2 (us3 never materialized) ----------
// 2 lanes/node; lane c: gather-sum us2 rows (chunk c), us3c = -2*d2*acc - us1c;
// partial acc10; shfl_xor(1) reduce; log_softmax; lane c writes out[n*10+c*5,5).
__global__ __launch_bounds__(BLK)
void prop_combine2_kernel(const int* __restrict__ rowbeg, const int* __restrict__ rowend,
                          const int* __restrict__ psrc, const float* __restrict__ d2,
                          const uint4* __restrict__ us2t, const uint4* __restrict__ us1t,
                          const uint4* __restrict__ hbt, const float* __restrict__ inv,
                          const float* __restrict__ W2, const float* __restrict__ b2,
                          float* __restrict__ out, int N) {
    __shared__ float sW[4 * 16 * 10];
    __shared__ float sb[10];
    for (int i = threadIdx.x; i < 4 * 16 * 10; i += blockDim.x) sW[i] = W2[i];
    if (threadIdx.x < 10) sb[threadIdx.x] = b2[threadIdx.x];
    __syncthreads();
    int t = blockIdx.x * blockDim.x + threadIdx.x;
    int n = t >> 1;
    int c = t & 1;
    if (n >= N) return;
    int beg = rowbeg[n];
    int end = rowend[n];
    float acc[8];
#pragma unroll
    for (int j = 0; j < 8; j++) acc[j] = 0.f;
    int i = beg;
    for (; i + 7 < end; i += 8) {
        int s0 = psrc[i],     s1 = psrc[i + 1], s2 = psrc[i + 2], s3 = psrc[i + 3];
        int s4 = psrc[i + 4], s5 = psrc[i + 5], s6 = psrc[i + 6], s7 = psrc[i + 7];
        uint4 a0 = us2t[(size_t)s0 * 2 + c];
        uint4 a1 = us2t[(size_t)s1 * 2 + c];
        uint4 a2 = us2t[(size_t)s2 * 2 + c];
        uint4 a3 = us2t[(size_t)s3 * 2 + c];
        uint4 a4 = us2t[(size_t)s4 * 2 + c];
        uint4 a5 = us2t[(size_t)s5 * 2 + c];
        uint4 a6 = us2t[(size_t)s6 * 2 + c];
        uint4 a7 = us2t[(size_t)s7 * 2 + c];
        add8(a0, acc); add8(a1, acc); add8(a2, acc); add8(a3, acc);
        add8(a4, acc); add8(a5, acc); add8(a6, acc); add8(a7, acc);
    }
    for (; i < end; i++) add8(us2t[(size_t)psrc[i] * 2 + c], acc);
    float f = -2.0f * d2[n];
    float p1[8], p2[8], ph[8], r[8];
    unpack8(us1t[(size_t)n * 2 + c], p1);
    unpack8(us2t[(size_t)n * 2 + c], p2);
    unpack8(hbt[(size_t)n * 2 + c], ph);
#pragma unroll
    for (int j = 0; j < 8; j++) r[j] = f * acc[j] - p1[j];   // us3 chunk, fp32
    float a10[10];
#pragma unroll
    for (int o = 0; o < 10; o++) a10[o] = (c == 0) ? sb[o] : 0.0f;
    float iv = inv[n];
    const float* W0 = sW + (c * 8) * 10;
#pragma unroll
    for (int j = 0; j < 8; j++) {
        float w0 = ph[j];
        float w1 = p1[j] * iv;
        float w2 = p2[j] * iv;
        float w3 = r[j] * iv;
        const float* Wj = W0 + j * 10;
#pragma unroll
        for (int o = 0; o < 10; o++)
            a10[o] += w0 * Wj[o] + w1 * Wj[160 + o] + w2 * Wj[320 + o] + w3 * Wj[480 + o];
    }
    if (iv == 0.0f) {  // deg-0 (rare): S2 = -h
#pragma unroll
        for (int j = 0; j < 8; j++) {
            const float* Wj = W0 + j * 10 + 320;
#pragma unroll
            for (int o = 0; o < 10; o++) a10[o] -= ph[j] * Wj[o];
        }
    }
#pragma unroll
    for (int o = 0; o < 10; o++) a10[o] += __shfl_xor(a10[o], 1);
    // log_softmax (both lanes compute; each writes its 5-output half)
    float m = a10[0];
#pragma unroll
    for (int o = 1; o < 10; o++) m = fmaxf(m, a10[o]);
    float sum = 0.0f;
#pragma unroll
    for (int o = 0; o < 10; o++) sum += expf(a10[o] - m);
    float lse = m + logf(sum);
    float* op = out + (size_t)n * 10 + c * 5;
#pragma unroll
    for (int o = 0; o < 5; o++) op[o] = a10[c * 5 + o] - lse;
}

extern "C" void kernel_launch(void* const* d_in, const int* in_sizes, int n_in,
                              void* d_out, int out_size, void* d_ws, size_t ws_size,
                              hipStream_t stream) {
    const float* x  = (const float*)d_in[0];
    const int*   ei = (const int*)d_in[1];
    const float* W1 = (const float*)d_in[2];
    const float* b1 = (const float*)d_in[3];
    const float* W2 = (const float*)d_in[4];
    const float* b2 = (const float*)d_in[5];
    float* out = (float*)d_out;

    const int N = in_sizes[0] / 32;   // 100000
    const int E = in_sizes[1] / 2;    // 1600000
    const int* src = ei;
    const int* dst = ei + E;

    const int nbuck = (N + 511) / 512;        // 196

    // workspace layout (16B-aligned regions)
    char* w = (char*)d_ws;
    int*   bfill  = (int*)w;              w += NBUCK_MAX * 4;
    int*   rowbeg = (int*)w;              w += (size_t)(N + 4) * 4;
    int*   rowend = (int*)w;              w += (size_t)(N + 4) * 4;
    float* dis    = (float*)w;            w += (size_t)N * 4;
    float* d2     = (float*)w;            w += (size_t)N * 4;
    float* inv    = (float*)w;            w += (size_t)N * 4;
    int*   tmp    = (int*)w;              w += (size_t)NBUCK_MAX * CAPB * 4;
    int*   psrc   = (int*)w;              w += (size_t)NBUCK_MAX * CAPB * 4;
    uint4* u0     = (uint4*)w;            w += (size_t)64 * N;   // 32 bf16 = 64B rows
    uint4* u1     = (uint4*)w;            w += (size_t)64 * N;
    uint4* u2     = (uint4*)w;            w += (size_t)64 * N;
    uint4* hb     = (uint4*)w;            w += (size_t)32 * N;   // 16 bf16 = 32B rows
    uint4* uh     = (uint4*)w;            w += (size_t)32 * N;
    uint4* us1    = (uint4*)w;            w += (size_t)32 * N;
    uint4* us2    = (uint4*)w;            w += (size_t)32 * N;

    int gU32 = (N * 4 + BLK - 1) / BLK;   // 4 lanes/node
    int gU16 = (N * 2 + BLK - 1) / BLK;   // 2 lanes/node
    int gCH  = (E + CHUNK - 1) / CHUNK;

    // ---- CSR build (2 kernels; u0 conversion fused into bucket_place) ----
    hipMemsetAsync(bfill, 0, NBUCK_MAX * sizeof(int), stream);
    binned_scatter_kernel<<<gCH, BLK, 0, stream>>>(src, dst, bfill, tmp, E, nbuck);
    bucket_place_kernel<<<nbuck, BLKP, 0, stream>>>(bfill, tmp, psrc, rowbeg, rowend,
                                                    dis, d2, inv, x, u0, N);

    // ---- layer 1 (F=32, bf16 U-tables, 64B rows) ----
    prop_u_kernel<4, false><<<gU32, BLK, 0, stream>>>(rowbeg, rowend, psrc, d2, u0, nullptr, u1, 1.0f, N);
    prop_u_kernel<4, true ><<<gU32, BLK, 0, stream>>>(rowbeg, rowend, psrc, d2, u1, u0,      u2, 2.0f, N);
    prop_combine1_kernel<<<gU32, BLK, 0, stream>>>(rowbeg, rowend, psrc, d2, u2, u1,
                                                   x, inv, dis, W1, b1, hb, uh, N);

    // ---- layer 2 (F=16, bf16 U-tables, 32B rows) ----
    prop_u_kernel<2, false><<<gU16, BLK, 0, stream>>>(rowbeg, rowend, psrc, d2, uh,  nullptr, us1, 1.0f, N);
    prop_u_kernel<2, true ><<<gU16, BLK, 0, stream>>>(rowbeg, rowend, psrc, d2, us1, uh,      us2, 2.0f, N);
    prop_combine2_kernel<<<gU16, BLK, 0, stream>>>(rowbeg, rowend, psrc, d2, us2, us1,
                                                   hb, inv, W2, b2, out, N);
}

// Round 17
// 283.948 us; speedup vs baseline: 1.0411x; 1.0411x over previous
//
#include <hip/hip_runtime.h>
#include <hip/hip_bf16.h>
#include <math.h>

// ChebyNet: 2-layer ChebConv (K=4), N=100000, E=1600000, F 32->16->10, log_softmax.
//
// R17: selective revert of R16. prop_combine1 had 9.6M LDS bank conflicts
// (lane weight-slab stride c*128 floats = 0 mod 32 banks -> every weight read
// 4-way serialized) + occupancy 18% (VGPR 128) -> 84us. Layer 1 reverts to
// R15's split (prop_u<4> + 2-threads/node combine1: wave-uniform broadcast
// weight reads, conflict-free, high occupancy). Layer 2 KEEPS the R16 fusion:
// prop_combine2's slab stride is 80 = 16 mod 32 -> conflict-free, and it
// saves us3 materialization + one launch.
// Rest = R15: U-space recurrence, src-quartile-ordered edges, bf16 tables
// (64B rows L1, 32B rows L2), fixed-capacity bucket CSR build + fused u0,
// 8-edges-in-flight props, __launch_bounds__ everywhere.

#define BLK 256
#define BLKP 512
#define NBUCK_MAX 256   // buckets = ceil(N/512); requires N <= 131072
#define CHUNK 8192      // edges per binned_scatter block
#define CAPB 16384      // fixed capacity per bucket region in tmp/psrc
#define PLACE_CAP 10240 // LDS staging capacity in bucket_place (avg bucket 8192)

// ---------- bf16 helpers (storage-only quantization) ----------
__device__ inline unsigned short f32_to_bf16_rne(float f) {
    unsigned int u = __float_as_uint(f);
    unsigned int rounding = 0x7FFFu + ((u >> 16) & 1u);
    return (unsigned short)((u + rounding) >> 16);
}
__device__ inline unsigned int pack_bf16x2(float a, float b) {
    return (unsigned int)f32_to_bf16_rne(a) | ((unsigned int)f32_to_bf16_rne(b) << 16);
}
__device__ inline void unpack8(const uint4 u, float* f) {
    const unsigned int* p = &u.x;
#pragma unroll
    for (int j = 0; j < 4; j++) {
        unsigned int w = p[j];
        f[2 * j]     = __uint_as_float(w << 16);
        f[2 * j + 1] = __uint_as_float(w & 0xFFFF0000u);
    }
}
__device__ inline void add8(const uint4 u, float* acc) {
    const unsigned int* p = &u.x;
#pragma unroll
    for (int j = 0; j < 4; j++) {
        unsigned int w = p[j];
        acc[2 * j]     += __uint_as_float(w << 16);
        acc[2 * j + 1] += __uint_as_float(w & 0xFFFF0000u);
    }
}
__device__ inline uint4 pack8(const float* r) {
    uint4 o;
    o.x = pack_bf16x2(r[0], r[1]);
    o.y = pack_bf16x2(r[2], r[3]);
    o.z = pack_bf16x2(r[4], r[5]);
    o.w = pack_bf16x2(r[6], r[7]);
    return o;
}

// FMA one bf16x8 chunk (scaled s) vs 8x16 slab, but only 8 output cols (stride 16)
__device__ inline void fma8_w8(const uint4 u, float s, const float* __restrict__ W,
                               float* acc) {
    const unsigned int* p = &u.x;
#pragma unroll
    for (int q = 0; q < 4; q++) {
        float fa = __uint_as_float(p[q] << 16) * s;
        float fb = __uint_as_float(p[q] & 0xFFFF0000u) * s;
        const float* Wa = W + (2 * q) * 16;
        const float* Wb = W + (2 * q + 1) * 16;
#pragma unroll
        for (int j = 0; j < 8; j++) acc[j] += fa * Wa[j] + fb * Wb[j];
    }
}

// ---------- CSR build (fixed-capacity buckets) ----------
__global__ __launch_bounds__(BLK)
void binned_scatter_kernel(const int* __restrict__ src, const int* __restrict__ dst,
                           int* __restrict__ bfill, int* __restrict__ tmp,
                           int E, int nbuck) {
    __shared__ int cnt[NBUCK_MAX];
    __shared__ int lofs[NBUCK_MAX + 1];
    __shared__ int pos[NBUCK_MAX];
    __shared__ int gbase[NBUCK_MAX];
    __shared__ int stage[CHUNK];
    __shared__ unsigned char bkt[CHUNK];

    int tid = threadIdx.x;
    int e0 = blockIdx.x * CHUNK;
    int nE = min(CHUNK, E - e0);

    for (int b = tid; b < nbuck; b += BLK) { cnt[b] = 0; pos[b] = 0; }
    __syncthreads();

    for (int i = tid; i < nE; i += BLK) {
        int d = dst[e0 + i];
        atomicAdd(&cnt[d >> 9], 1);
    }
    __syncthreads();

    {
        int v = (tid < nbuck) ? cnt[tid] : 0;
        lofs[tid] = v;
        __syncthreads();
        for (int off = 1; off < BLK; off <<= 1) {
            int t = (tid >= off) ? lofs[tid - off] : 0;
            __syncthreads();
            lofs[tid] += t;
            __syncthreads();
        }
        int incl = lofs[tid];
        __syncthreads();
        lofs[tid] = incl - v;
        if (tid == 0) lofs[nbuck] = nE;
        if (tid < nbuck && v > 0)
            gbase[tid] = tid * CAPB + atomicAdd(&bfill[tid], v);
    }
    __syncthreads();

    for (int i = tid; i < nE; i += BLK) {
        int s = src[e0 + i];
        int d = dst[e0 + i];
        int b = d >> 9;
        int slot = lofs[b] + atomicAdd(&pos[b], 1);
        stage[slot] = (s << 9) | (d & 511);
        bkt[slot] = (unsigned char)b;
    }
    __syncthreads();

    for (int i = tid; i < nE; i += BLK) {
        int b = bkt[i];
        tmp[gbase[b] + (i - lofs[b])] = stage[i];
    }
}

// Phase 2: per-bucket degree count/scan -> rowbeg/rowend/dis/d2/inv + fused u0;
// rank+stage+flush psrc with each node's edges ordered by src quartile.
__global__ __launch_bounds__(BLKP)
void bucket_place_kernel(const int* __restrict__ bfill, const int* __restrict__ tmp,
                         int* __restrict__ psrc, int* __restrict__ rowbeg,
                         int* __restrict__ rowend, float* __restrict__ dis,
                         float* __restrict__ d2, float* __restrict__ inv,
                         const float* __restrict__ x, uint4* __restrict__ u0, int N) {
    __shared__ int cnt4[512 * 4];
    __shared__ int ofs[512];
    __shared__ int fill4[512 * 4];
    __shared__ int stage[PLACE_CAP];

    int b = blockIdx.x;
    int tid = threadIdx.x;
    int n0 = b << 9;
    int nn = min(512, N - n0);
    int S = b * CAPB;
    int tot = bfill[b];

    int t1 = N >> 2, t2 = N >> 1, t3 = t2 + t1;

    for (int i = tid; i < 512 * 4; i += BLKP) { cnt4[i] = 0; fill4[i] = 0; }
    __syncthreads();

    for (int i = tid; i < tot; i += BLKP) {
        int rec = tmp[S + i];
        int nl = rec & 511;
        int s = rec >> 9;
        int q = (s >= t2) ? ((s >= t3) ? 3 : 2) : ((s >= t1) ? 1 : 0);
        atomicAdd(&cnt4[nl * 4 + q], 1);
    }
    __syncthreads();

    int c0 = cnt4[tid * 4 + 0], c1 = cnt4[tid * 4 + 1];
    int c2 = cnt4[tid * 4 + 2], c3 = cnt4[tid * 4 + 3];
    int v = c0 + c1 + c2 + c3;
    cnt4[tid * 4 + 0] = 0;
    cnt4[tid * 4 + 1] = c0;
    cnt4[tid * 4 + 2] = c0 + c1;
    cnt4[tid * 4 + 3] = c0 + c1 + c2;
    ofs[tid] = v;
    __syncthreads();
    for (int off = 1; off < 512; off <<= 1) {
        int t = (tid >= off) ? ofs[tid - off] : 0;
        __syncthreads();
        ofs[tid] += t;
        __syncthreads();
    }
    int excl = ofs[tid] - v;
    __syncthreads();
    ofs[tid] = excl;
    float dn = (v > 0) ? rsqrtf((float)v) : 0.0f;
    if (tid < nn) {
        int n = n0 + tid;
        rowbeg[n] = S + excl;
        rowend[n] = S + excl + v;
        float fv = (float)v;
        dis[n] = dn;
        d2[n]  = (v > 0) ? 1.0f / fv : 0.0f;
        inv[n] = (v > 0) ? sqrtf(fv) : 0.0f;
        const float4* xr = reinterpret_cast<const float4*>(x + (size_t)n * 32);
#pragma unroll
        for (int c = 0; c < 4; c++) {
            float4 a = xr[c * 2], bb = xr[c * 2 + 1];
            float r[8] = {dn * a.x, dn * a.y, dn * a.z, dn * a.w,
                          dn * bb.x, dn * bb.y, dn * bb.z, dn * bb.w};
            u0[(size_t)n * 4 + c] = pack8(r);
        }
    }
    __syncthreads();

    if (tot <= PLACE_CAP) {
        for (int i = tid; i < tot; i += BLKP) {
            int rec = tmp[S + i];
            int nl = rec & 511;
            int s = rec >> 9;
            int q = (s >= t2) ? ((s >= t3) ? 3 : 2) : ((s >= t1) ? 1 : 0);
            int slot = ofs[nl] + cnt4[nl * 4 + q] + atomicAdd(&fill4[nl * 4 + q], 1);
            stage[slot] = s;
        }
        __syncthreads();
        for (int i = tid; i < tot; i += BLKP) psrc[S + i] = stage[i];
    } else {
        for (int i = tid; i < tot; i += BLKP) {
            int rec = tmp[S + i];
            int nl = rec & 511;
            int s = rec >> 9;
            int q = (s >= t2) ? ((s >= t3) ? 3 : 2) : ((s >= t1) ? 1 : 0);
            int slot = S + ofs[nl] + cnt4[nl * 4 + q] + atomicAdd(&fill4[nl * 4 + q], 1);
            psrc[slot] = s;
        }
    }
}

// ---------- U-space props: pure gather-sum, 8 edges in flight ----------
template <int C, bool HAVE_PREV>
__global__ __launch_bounds__(BLK)
void prop_u_kernel(const int* __restrict__ rowbeg, const int* __restrict__ rowend,
                   const int* __restrict__ psrc, const float* __restrict__ d2,
                   const uint4* __restrict__ vb, const uint4* __restrict__ prevb,
                   uint4* __restrict__ outb, float scale, int N) {
    int t = blockIdx.x * blockDim.x + threadIdx.x;
    int n = t / C;
    int c = t % C;
    if (n >= N) return;
    int beg = rowbeg[n];
    int end = rowend[n];
    float acc[8];
#pragma unroll
    for (int j = 0; j < 8; j++) acc[j] = 0.f;
    int i = beg;
    for (; i + 7 < end; i += 8) {
        int s0 = psrc[i],     s1 = psrc[i + 1], s2 = psrc[i + 2], s3 = psrc[i + 3];
        int s4 = psrc[i + 4], s5 = psrc[i + 5], s6 = psrc[i + 6], s7 = psrc[i + 7];
        uint4 a0 = vb[(size_t)s0 * C + c];
        uint4 a1 = vb[(size_t)s1 * C + c];
        uint4 a2 = vb[(size_t)s2 * C + c];
        uint4 a3 = vb[(size_t)s3 * C + c];
        uint4 a4 = vb[(size_t)s4 * C + c];
        uint4 a5 = vb[(size_t)s5 * C + c];
        uint4 a6 = vb[(size_t)s6 * C + c];
        uint4 a7 = vb[(size_t)s7 * C + c];
        add8(a0, acc); add8(a1, acc); add8(a2, acc); add8(a3, acc);
        add8(a4, acc); add8(a5, acc); add8(a6, acc); add8(a7, acc);
    }
    for (; i + 3 < end; i += 4) {
        int s0 = psrc[i], s1 = psrc[i + 1], s2 = psrc[i + 2], s3 = psrc[i + 3];
        uint4 a0 = vb[(size_t)s0 * C + c];
        uint4 a1 = vb[(size_t)s1 * C + c];
        uint4 a2 = vb[(size_t)s2 * C + c];
        uint4 a3 = vb[(size_t)s3 * C + c];
        add8(a0, acc); add8(a1, acc); add8(a2, acc); add8(a3, acc);
    }
    for (; i < end; i++) {
        uint4 a0 = vb[(size_t)psrc[i] * C + c];
        add8(a0, acc);
    }
    float f = -scale * d2[n];
    float r[8];
    if (HAVE_PREV) {
        float p[8];
        unpack8(prevb[(size_t)n * C + c], p);
#pragma unroll
        for (int j = 0; j < 8; j++) r[j] = f * acc[j] - p[j];
    } else {
#pragma unroll
        for (int j = 0; j < 8; j++) r[j] = f * acc[j];
    }
    outb[(size_t)n * C + c] = pack8(r);
}

// h = relu(b1 + x@W1[0] + sum_{k=1..3} (Uk*inv)@W1[k]); deg-0: Tx2=-x.
// 2 threads/node (outputs split 8+8); wave-uniform (broadcast) weight reads.
__global__ __launch_bounds__(BLK)
void combine1_kernel(const float* __restrict__ x, const uint4* __restrict__ u1,
                     const uint4* __restrict__ u2, const uint4* __restrict__ u3,
                     const float* __restrict__ inv, const float* __restrict__ dis,
                     const float* __restrict__ W1, const float* __restrict__ b1,
                     uint4* __restrict__ hb, uint4* __restrict__ uh, int N) {
    __shared__ float sW[4 * 32 * 16];
    __shared__ float sb[16];
    for (int i = threadIdx.x; i < 4 * 32 * 16; i += blockDim.x) sW[i] = W1[i];
    if (threadIdx.x < 16) sb[threadIdx.x] = b1[threadIdx.x];
    __syncthreads();
    int t = blockIdx.x * blockDim.x + threadIdx.x;
    int n = t >> 1;
    int h = t & 1;          // output half
    if (n >= N) return;
    const float* sWh = sW + h * 8;   // column offset
    float acc[8];
#pragma unroll
    for (int j = 0; j < 8; j++) acc[j] = sb[h * 8 + j];
    {
        const float4* in4 = reinterpret_cast<const float4*>(x + (size_t)n * 32);
#pragma unroll
        for (int q = 0; q < 8; q++) {
            float4 a = in4[q];
            const float* Wq = sWh + q * 4 * 16;
#pragma unroll
            for (int j = 0; j < 8; j++)
                acc[j] += a.x * Wq[j] + a.y * Wq[16 + j] + a.z * Wq[32 + j] + a.w * Wq[48 + j];
        }
    }
    float iv = inv[n];
#pragma unroll
    for (int c = 0; c < 4; c++) fma8_w8(u1[(size_t)n * 4 + c], iv, sWh + 512 + c * 128, acc);
#pragma unroll
    for (int c = 0; c < 4; c++) fma8_w8(u2[(size_t)n * 4 + c], iv, sWh + 1024 + c * 128, acc);
#pragma unroll
    for (int c = 0; c < 4; c++) fma8_w8(u3[(size_t)n * 4 + c], iv, sWh + 1536 + c * 128, acc);
    if (iv == 0.0f) {  // deg-0 (rare): Tx2 = -x; Tx1 = Tx3 = 0 already
        const float4* in4 = reinterpret_cast<const float4*>(x + (size_t)n * 32);
#pragma unroll
        for (int q = 0; q < 8; q++) {
            float4 a = in4[q];
            const float* Wq = sWh + 1024 + q * 4 * 16;
#pragma unroll
            for (int j = 0; j < 8; j++)
                acc[j] -= a.x * Wq[j] + a.y * Wq[16 + j] + a.z * Wq[32 + j] + a.w * Wq[48 + j];
        }
    }
    float dn = dis[n];
    float r[8], u[8];
#pragma unroll
    for (int j = 0; j < 8; j++) {
        r[j] = fmaxf(acc[j], 0.0f);
        u[j] = dn * r[j];
    }
    hb[(size_t)n * 2 + h] = pack8(r);
    uh[(size_t)n * 2 + h] = pack8(u);
}

// ---------- Fused: us3-prop + combine2 (us3 never materialized) ----------
// 2 lanes/node; conflict-free weight slabs (stride 80 = 16 mod 32 banks).
__global__ __launch_bounds__(BLK)
void prop_combine2_kernel(const int* __restrict__ rowbeg, const int* __restrict__ rowend,
                          const int* __restrict__ psrc, const float* __restrict__ d2,
                          const uint4* __restrict__ us2t, const uint4* __restrict__ us1t,
                          const uint4* __restrict__ hbt, const float* __restrict__ inv,
                          const float* __restrict__ W2, const float* __restrict__ b2,
                          float* __restrict__ out, int N) {
    __shared__ float sW[4 * 16 * 10];
    __shared__ float sb[10];
    for (int i = threadIdx.x; i < 4 * 16 * 10; i += blockDim.x) sW[i] = W2[i];
    if (threadIdx.x < 10) sb[threadIdx.x] = b2[threadIdx.x];
    __syncthreads();
    int t = blockIdx.x * blockDim.x + threadIdx.x;
    int n = t >> 1;
    int c = t & 1;
    if (n >= N) return;
    int beg = rowbeg[n];
    int end = rowend[n];
    float acc[8];
#pragma unroll
    for (int j = 0; j < 8; j++) acc[j] = 0.f;
    int i = beg;
    for (; i + 7 < end; i += 8) {
        int s0 = psrc[i],     s1 = psrc[i + 1], s2 = psrc[i + 2], s3 = psrc[i + 3];
        int s4 = psrc[i + 4], s5 = psrc[i + 5], s6 = psrc[i + 6], s7 = psrc[i + 7];
        uint4 a0 = us2t[(size_t)s0 * 2 + c];
        uint4 a1 = us2t[(size_t)s1 * 2 + c];
        uint4 a2 = us2t[(size_t)s2 * 2 + c];
        uint4 a3 = us2t[(size_t)s3 * 2 + c];
        uint4 a4 = us2t[(size_t)s4 * 2 + c];
        uint4 a5 = us2t[(size_t)s5 * 2 + c];
        uint4 a6 = us2t[(size_t)s6 * 2 + c];
        uint4 a7 = us2t[(size_t)s7 * 2 + c];
        add8(a0, acc); add8(a1, acc); add8(a2, acc); add8(a3, acc);
        add8(a4, acc); add8(a5, acc); add8(a6, acc); add8(a7, acc);
    }
    for (; i < end; i++) add8(us2t[(size_t)psrc[i] * 2 + c], acc);
    float f = -2.0f * d2[n];
    float p1[8], p2[8], ph[8], r[8];
    unpack8(us1t[(size_t)n * 2 + c], p1);
    unpack8(us2t[(size_t)n * 2 + c], p2);
    unpack8(hbt[(size_t)n * 2 + c], ph);
#pragma unroll
    for (int j = 0; j < 8; j++) r[j] = f * acc[j] - p1[j];   // us3 chunk, fp32
    float a10[10];
#pragma unroll
    for (int o = 0; o < 10; o++) a10[o] = (c == 0) ? sb[o] : 0.0f;
    float iv = inv[n];
    const float* W0 = sW + (c * 8) * 10;
#pragma unroll
    for (int j = 0; j < 8; j++) {
        float w0 = ph[j];
        float w1 = p1[j] * iv;
        float w2 = p2[j] * iv;
        float w3 = r[j] * iv;
        const float* Wj = W0 + j * 10;
#pragma unroll
        for (int o = 0; o < 10; o++)
            a10[o] += w0 * Wj[o] + w1 * Wj[160 + o] + w2 * Wj[320 + o] + w3 * Wj[480 + o];
    }
    if (iv == 0.0f) {  // deg-0 (rare): S2 = -h
#pragma unroll
        for (int j = 0; j < 8; j++) {
            const float* Wj = W0 + j * 10 + 320;
#pragma unroll
            for (int o = 0; o < 10; o++) a10[o] -= ph[j] * Wj[o];
        }
    }
#pragma unroll
    for (int o = 0; o < 10; o++) a10[o] += __shfl_xor(a10[o], 1);
    float m = a10[0];
#pragma unroll
    for (int o = 1; o < 10; o++) m = fmaxf(m, a10[o]);
    float sum = 0.0f;
#pragma unroll
    for (int o = 0; o < 10; o++) sum += expf(a10[o] - m);
    float lse = m + logf(sum);
    float* op = out + (size_t)n * 10 + c * 5;
#pragma unroll
    for (int o = 0; o < 5; o++) op[o] = a10[c * 5 + o] - lse;
}

extern "C" void kernel_launch(void* const* d_in, const int* in_sizes, int n_in,
                              void* d_out, int out_size, void* d_ws, size_t ws_size,
                              hipStream_t stream) {
    const float* x  = (const float*)d_in[0];
    const int*   ei = (const int*)d_in[1];
    const float* W1 = (const float*)d_in[2];
    const float* b1 = (const float*)d_in[3];
    const float* W2 = (const float*)d_in[4];
    const float* b2 = (const float*)d_in[5];
    float* out = (float*)d_out;

    const int N = in_sizes[0] / 32;   // 100000
    const int E = in_sizes[1] / 2;    // 1600000
    const int* src = ei;
    const int* dst = ei + E;

    const int nbuck = (N + 511) / 512;        // 196

    // workspace layout (16B-aligned regions)
    char* w = (char*)d_ws;
    int*   bfill  = (int*)w;              w += NBUCK_MAX * 4;
    int*   rowbeg = (int*)w;              w += (size_t)(N + 4) * 4;
    int*   rowend = (int*)w;              w += (size_t)(N + 4) * 4;
    float* dis    = (float*)w;            w += (size_t)N * 4;
    float* d2     = (float*)w;            w += (size_t)N * 4;
    float* inv    = (float*)w;            w += (size_t)N * 4;
    int*   tmp    = (int*)w;              w += (size_t)NBUCK_MAX * CAPB * 4;
    int*   psrc   = (int*)w;              w += (size_t)NBUCK_MAX * CAPB * 4;
    uint4* u0     = (uint4*)w;            w += (size_t)64 * N;   // 32 bf16 = 64B rows
    uint4* u1     = (uint4*)w;            w += (size_t)64 * N;
    uint4* u2     = (uint4*)w;            w += (size_t)64 * N;
    uint4* u3     = (uint4*)w;            w += (size_t)64 * N;
    uint4* hb     = (uint4*)w;            w += (size_t)32 * N;   // 16 bf16 = 32B rows
    uint4* uh     = (uint4*)w;            w += (size_t)32 * N;
    uint4* us1    = (uint4*)w;            w += (size_t)32 * N;
    uint4* us2    = (uint4*)w;            w += (size_t)32 * N;

    int gN2  = (N * 2 + BLK - 1) / BLK;   // combine1 / 2-lanes-per-node kernels
    int gU32 = (N * 4 + BLK - 1) / BLK;   // 4 lanes/node
    int gU16 = (N * 2 + BLK - 1) / BLK;   // 2 lanes/node
    int gCH  = (E + CHUNK - 1) / CHUNK;

    // ---- CSR build (2 kernels; u0 conversion fused into bucket_place) ----
    hipMemsetAsync(bfill, 0, NBUCK_MAX * sizeof(int), stream);
    binned_scatter_kernel<<<gCH, BLK, 0, stream>>>(src, dst, bfill, tmp, E, nbuck);
    bucket_place_kernel<<<nbuck, BLKP, 0, stream>>>(bfill, tmp, psrc, rowbeg, rowend,
                                                    dis, d2, inv, x, u0, N);

    // ---- layer 1 (F=32, bf16 U-tables, 64B rows; split prop/combine) ----
    prop_u_kernel<4, false><<<gU32, BLK, 0, stream>>>(rowbeg, rowend, psrc, d2, u0, nullptr, u1, 1.0f, N);
    prop_u_kernel<4, true ><<<gU32, BLK, 0, stream>>>(rowbeg, rowend, psrc, d2, u1, u0,      u2, 2.0f, N);
    prop_u_kernel<4, true ><<<gU32, BLK, 0, stream>>>(rowbeg, rowend, psrc, d2, u2, u1,      u3, 2.0f, N);
    combine1_kernel<<<gN2, BLK, 0, stream>>>(x, u1, u2, u3, inv, dis, W1, b1, hb, uh, N);

    // ---- layer 2 (F=16, bf16 U-tables, 32B rows; fused tail) ----
    prop_u_kernel<2, false><<<gU16, BLK, 0, stream>>>(rowbeg, rowend, psrc, d2, uh,  nullptr, us1, 1.0f, N);
    prop_u_kernel<2, true ><<<gU16, BLK, 0, stream>>>(rowbeg, rowend, psrc, d2, us1, uh,      us2, 2.0f, N);
    prop_combine2_kernel<<<gU16, BLK, 0, stream>>>(rowbeg, rowend, psrc, d2, us2, us1,
                                                   hb, inv, W2, b2, out, N);
}

// Round 18
// 250.834 us; speedup vs baseline: 1.1786x; 1.1320x over previous
//
#include <hip/hip_runtime.h>
#include <hip/hip_bf16.h>
#include <math.h>

// ChebyNet: 2-layer ChebConv (K=4), N=100000, E=1600000, F 32->16->10, log_softmax.
//
// R18: CLENSHAW restructure. T_k(L) commutes with @W_k, so compute
// z_k = x@W1[k] FIRST (dense, coalesced), then evaluate S = sum_k T_k(L) z_k
// via Clenshaw: b3=z3; b2=z2+2Lb3; b1=z1+2Lb2-b3; S=z0+Lb1-b2. All three
// propagations now run in the 16-feature domain: 32B bf16 rows -> 3.2MB
// tables that FIT the 4MB/XCD L2 (the 6.4MB F=32 tables were the R14-R17
// bottleneck). U-space folding kept: Ub_k = uz_k - 2*d2*Sum Ub_{k+1}[src]
// - Ub_{k+2}; S = z0 - dis*Sum Ub1[src] - inv*Ub2. Combines are elementwise
// (weights pre-applied): final1 = last gather + relu + w_k=h@W2[k] gen
// (2-way LDS reads only -- free; R16's 4-way conflict lesson); final2 =
// last gather + log_softmax. deg-0 exact via raw z2/w2 tables (S = z0 - z2).
// Build = R15: fixed-capacity buckets, src-quartile edge ordering.

#define BLK 256
#define BLKP 512
#define NBUCK_MAX 256   // buckets = ceil(N/512); requires N <= 131072
#define CHUNK 8192      // edges per binned_scatter block
#define CAPB 16384      // fixed capacity per bucket region in tmp/psrc
#define PLACE_CAP 10240 // LDS staging capacity in bucket_place (avg bucket 8192)

// ---------- bf16 helpers (storage-only quantization) ----------
__device__ inline unsigned short f32_to_bf16_rne(float f) {
    unsigned int u = __float_as_uint(f);
    unsigned int rounding = 0x7FFFu + ((u >> 16) & 1u);
    return (unsigned short)((u + rounding) >> 16);
}
__device__ inline unsigned int pack_bf16x2(float a, float b) {
    return (unsigned int)f32_to_bf16_rne(a) | ((unsigned int)f32_to_bf16_rne(b) << 16);
}
__device__ inline void unpack8(const uint4 u, float* f) {
    const unsigned int* p = &u.x;
#pragma unroll
    for (int j = 0; j < 4; j++) {
        unsigned int w = p[j];
        f[2 * j]     = __uint_as_float(w << 16);
        f[2 * j + 1] = __uint_as_float(w & 0xFFFF0000u);
    }
}
__device__ inline void add8(const uint4 u, float* acc) {
    const unsigned int* p = &u.x;
#pragma unroll
    for (int j = 0; j < 4; j++) {
        unsigned int w = p[j];
        acc[2 * j]     += __uint_as_float(w << 16);
        acc[2 * j + 1] += __uint_as_float(w & 0xFFFF0000u);
    }
}
__device__ inline uint4 pack8(const float* r) {
    uint4 o;
    o.x = pack_bf16x2(r[0], r[1]);
    o.y = pack_bf16x2(r[2], r[3]);
    o.z = pack_bf16x2(r[4], r[5]);
    o.w = pack_bf16x2(r[6], r[7]);
    return o;
}

// ---------- CSR build (fixed-capacity buckets) ----------
__global__ __launch_bounds__(BLK)
void binned_scatter_kernel(const int* __restrict__ src, const int* __restrict__ dst,
                           int* __restrict__ bfill, int* __restrict__ tmp,
                           int E, int nbuck) {
    __shared__ int cnt[NBUCK_MAX];
    __shared__ int lofs[NBUCK_MAX + 1];
    __shared__ int pos[NBUCK_MAX];
    __shared__ int gbase[NBUCK_MAX];
    __shared__ int stage[CHUNK];
    __shared__ unsigned char bkt[CHUNK];

    int tid = threadIdx.x;
    int e0 = blockIdx.x * CHUNK;
    int nE = min(CHUNK, E - e0);

    for (int b = tid; b < nbuck; b += BLK) { cnt[b] = 0; pos[b] = 0; }
    __syncthreads();

    for (int i = tid; i < nE; i += BLK) {
        int d = dst[e0 + i];
        atomicAdd(&cnt[d >> 9], 1);
    }
    __syncthreads();

    {
        int v = (tid < nbuck) ? cnt[tid] : 0;
        lofs[tid] = v;
        __syncthreads();
        for (int off = 1; off < BLK; off <<= 1) {
            int t = (tid >= off) ? lofs[tid - off] : 0;
            __syncthreads();
            lofs[tid] += t;
            __syncthreads();
        }
        int incl = lofs[tid];
        __syncthreads();
        lofs[tid] = incl - v;
        if (tid == 0) lofs[nbuck] = nE;
        if (tid < nbuck && v > 0)
            gbase[tid] = tid * CAPB + atomicAdd(&bfill[tid], v);
    }
    __syncthreads();

    for (int i = tid; i < nE; i += BLK) {
        int s = src[e0 + i];
        int d = dst[e0 + i];
        int b = d >> 9;
        int slot = lofs[b] + atomicAdd(&pos[b], 1);
        stage[slot] = (s << 9) | (d & 511);
        bkt[slot] = (unsigned char)b;
    }
    __syncthreads();

    for (int i = tid; i < nE; i += BLK) {
        int b = bkt[i];
        tmp[gbase[b] + (i - lofs[b])] = stage[i];
    }
}

// Phase 2: per-bucket degree count/scan -> rowbeg/rowend/dis/d2/inv;
// rank+stage+flush psrc with each node's edges ordered by src quartile.
__global__ __launch_bounds__(BLKP)
void bucket_place_kernel(const int* __restrict__ bfill, const int* __restrict__ tmp,
                         int* __restrict__ psrc, int* __restrict__ rowbeg,
                         int* __restrict__ rowend, float* __restrict__ dis,
                         float* __restrict__ d2, float* __restrict__ inv, int N) {
    __shared__ int cnt4[512 * 4];
    __shared__ int ofs[512];
    __shared__ int fill4[512 * 4];
    __shared__ int stage[PLACE_CAP];

    int b = blockIdx.x;
    int tid = threadIdx.x;
    int n0 = b << 9;
    int nn = min(512, N - n0);
    int S = b * CAPB;
    int tot = bfill[b];

    int t1 = N >> 2, t2 = N >> 1, t3 = t2 + t1;

    for (int i = tid; i < 512 * 4; i += BLKP) { cnt4[i] = 0; fill4[i] = 0; }
    __syncthreads();

    for (int i = tid; i < tot; i += BLKP) {
        int rec = tmp[S + i];
        int nl = rec & 511;
        int s = rec >> 9;
        int q = (s >= t2) ? ((s >= t3) ? 3 : 2) : ((s >= t1) ? 1 : 0);
        atomicAdd(&cnt4[nl * 4 + q], 1);
    }
    __syncthreads();

    int c0 = cnt4[tid * 4 + 0], c1 = cnt4[tid * 4 + 1];
    int c2 = cnt4[tid * 4 + 2], c3 = cnt4[tid * 4 + 3];
    int v = c0 + c1 + c2 + c3;
    cnt4[tid * 4 + 0] = 0;
    cnt4[tid * 4 + 1] = c0;
    cnt4[tid * 4 + 2] = c0 + c1;
    cnt4[tid * 4 + 3] = c0 + c1 + c2;
    ofs[tid] = v;
    __syncthreads();
    for (int off = 1; off < 512; off <<= 1) {
        int t = (tid >= off) ? ofs[tid - off] : 0;
        __syncthreads();
        ofs[tid] += t;
        __syncthreads();
    }
    int excl = ofs[tid] - v;
    __syncthreads();
    ofs[tid] = excl;
    if (tid < nn) {
        int n = n0 + tid;
        rowbeg[n] = S + excl;
        rowend[n] = S + excl + v;
        float fv = (float)v;
        dis[n] = (v > 0) ? rsqrtf(fv) : 0.0f;
        d2[n]  = (v > 0) ? 1.0f / fv : 0.0f;
        inv[n] = (v > 0) ? sqrtf(fv) : 0.0f;
    }
    __syncthreads();

    if (tot <= PLACE_CAP) {
        for (int i = tid; i < tot; i += BLKP) {
            int rec = tmp[S + i];
            int nl = rec & 511;
            int s = rec >> 9;
            int q = (s >= t2) ? ((s >= t3) ? 3 : 2) : ((s >= t1) ? 1 : 0);
            int slot = ofs[nl] + cnt4[nl * 4 + q] + atomicAdd(&fill4[nl * 4 + q], 1);
            stage[slot] = s;
        }
        __syncthreads();
        for (int i = tid; i < tot; i += BLKP) psrc[S + i] = stage[i];
    } else {
        for (int i = tid; i < tot; i += BLKP) {
            int rec = tmp[S + i];
            int nl = rec & 511;
            int s = rec >> 9;
            int q = (s >= t2) ? ((s >= t3) ? 3 : 2) : ((s >= t1) ? 1 : 0);
            int slot = S + ofs[nl] + cnt4[nl * 4 + q] + atomicAdd(&fill4[nl * 4 + q], 1);
            psrc[slot] = s;
        }
    }
}

// z_k = x @ W1[k] for k=0..3; 2 lanes/node (8 outputs each).
// Writes z0 (raw), uz1/uz2/uz3 (dis-scaled), z2r (raw, deg-0 fallback).
__global__ __launch_bounds__(BLK)
void zgen_kernel(const float* __restrict__ x, const float* __restrict__ dis,
                 const float* __restrict__ W1,
                 uint4* __restrict__ z0t, uint4* __restrict__ uz1t,
                 uint4* __restrict__ uz2t, uint4* __restrict__ uz3t,
                 uint4* __restrict__ z2rt, int N) {
    __shared__ float sW[4 * 32 * 16];
    for (int i = threadIdx.x; i < 4 * 32 * 16; i += blockDim.x) sW[i] = W1[i];
    __syncthreads();
    int t = blockIdx.x * blockDim.x + threadIdx.x;
    int n = t >> 1;
    int h = t & 1;
    if (n >= N) return;
    float acc0[8], acc1[8], acc2[8], acc3[8];
#pragma unroll
    for (int j = 0; j < 8; j++) { acc0[j] = 0.f; acc1[j] = 0.f; acc2[j] = 0.f; acc3[j] = 0.f; }
    const float4* x4 = reinterpret_cast<const float4*>(x + (size_t)n * 32);
#pragma unroll
    for (int q = 0; q < 8; q++) {
        float4 a = x4[q];
        float xi[4] = {a.x, a.y, a.z, a.w};
#pragma unroll
        for (int u = 0; u < 4; u++) {
            const float* Wb = sW + (q * 4 + u) * 16 + h * 8;
            float xv = xi[u];
#pragma unroll
            for (int j = 0; j < 8; j++) {
                acc0[j] += xv * Wb[j];
                acc1[j] += xv * Wb[512 + j];
                acc2[j] += xv * Wb[1024 + j];
                acc3[j] += xv * Wb[1536 + j];
            }
        }
    }
    float dn = dis[n];
    float s1[8], s2[8], s3[8];
#pragma unroll
    for (int j = 0; j < 8; j++) { s1[j] = dn * acc1[j]; s2[j] = dn * acc2[j]; s3[j] = dn * acc3[j]; }
    size_t o = (size_t)n * 2 + h;
    z0t[o]  = pack8(acc0);
    uz1t[o] = pack8(s1);
    uz2t[o] = pack8(s2);
    z2rt[o] = pack8(acc2);
    uz3t[o] = pack8(s3);
}

// Clenshaw prop: out = -2*d2[n]*Sum_e vb[src] + addt[n] (- subt[n]). C=2.
template <bool HAVE_SUB>
__global__ __launch_bounds__(BLK)
void prop_cl_kernel(const int* __restrict__ rowbeg, const int* __restrict__ rowend,
                    const int* __restrict__ psrc, const float* __restrict__ d2,
                    const uint4* __restrict__ vb, const uint4* __restrict__ addt,
                    const uint4* __restrict__ subt, uint4* __restrict__ outb, int N) {
    int t = blockIdx.x * blockDim.x + threadIdx.x;
    int n = t >> 1;
    int c = t & 1;
    if (n >= N) return;
    int beg = rowbeg[n];
    int end = rowend[n];
    float acc[8];
#pragma unroll
    for (int j = 0; j < 8; j++) acc[j] = 0.f;
    int i = beg;
    for (; i + 7 < end; i += 8) {
        int s0 = psrc[i],     s1 = psrc[i + 1], s2 = psrc[i + 2], s3 = psrc[i + 3];
        int s4 = psrc[i + 4], s5 = psrc[i + 5], s6 = psrc[i + 6], s7 = psrc[i + 7];
        uint4 a0 = vb[(size_t)s0 * 2 + c];
        uint4 a1 = vb[(size_t)s1 * 2 + c];
        uint4 a2 = vb[(size_t)s2 * 2 + c];
        uint4 a3 = vb[(size_t)s3 * 2 + c];
        uint4 a4 = vb[(size_t)s4 * 2 + c];
        uint4 a5 = vb[(size_t)s5 * 2 + c];
        uint4 a6 = vb[(size_t)s6 * 2 + c];
        uint4 a7 = vb[(size_t)s7 * 2 + c];
        add8(a0, acc); add8(a1, acc); add8(a2, acc); add8(a3, acc);
        add8(a4, acc); add8(a5, acc); add8(a6, acc); add8(a7, acc);
    }
    for (; i < end; i++) add8(vb[(size_t)psrc[i] * 2 + c], acc);
    float f = -2.0f * d2[n];
    float ad[8], r[8];
    unpack8(addt[(size_t)n * 2 + c], ad);
    if (HAVE_SUB) {
        float sb[8];
        unpack8(subt[(size_t)n * 2 + c], sb);
#pragma unroll
        for (int j = 0; j < 8; j++) r[j] = f * acc[j] + ad[j] - sb[j];
    } else {
#pragma unroll
        for (int j = 0; j < 8; j++) r[j] = f * acc[j] + ad[j];
    }
    outb[(size_t)n * 2 + c] = pack8(r);
}

// final1: S = z0 - dis*Sum Ub1[src] - inv*Ub2 (deg-0: z0 - z2r); h = relu(b1+S);
// then w_k = h @ W2[k] (16-padded cols) -> w0 raw, uw1/uw2/uw3 dis-scaled, w2r raw.
__global__ __launch_bounds__(BLK)
void final1_kernel(const int* __restrict__ rowbeg, const int* __restrict__ rowend,
                   const int* __restrict__ psrc, const float* __restrict__ dis,
                   const float* __restrict__ d2, const float* __restrict__ inv,
                   const uint4* __restrict__ ub1t, const uint4* __restrict__ ub2t,
                   const uint4* __restrict__ z0t, const uint4* __restrict__ z2rt,
                   const float* __restrict__ W2, const float* __restrict__ b1,
                   uint4* __restrict__ w0t, uint4* __restrict__ uw1t,
                   uint4* __restrict__ uw2t, uint4* __restrict__ uw3t,
                   uint4* __restrict__ w2rt, int N) {
    __shared__ float sW[4 * 16 * 16];   // W2 padded to 16 cols (zeros beyond col 9)
    __shared__ float sb1[16];
    for (int i = threadIdx.x; i < 4 * 16 * 16; i += blockDim.x) {
        int k = i >> 8, rem = i & 255, j = rem >> 4, o = rem & 15;
        sW[i] = (o < 10) ? W2[k * 160 + j * 10 + o] : 0.0f;
    }
    if (threadIdx.x < 16) sb1[threadIdx.x] = b1[threadIdx.x];
    __syncthreads();
    int t = blockIdx.x * blockDim.x + threadIdx.x;
    int n = t >> 1;
    int h = t & 1;
    if (n >= N) return;
    int beg = rowbeg[n];
    int end = rowend[n];
    float acc[8];
#pragma unroll
    for (int j = 0; j < 8; j++) acc[j] = 0.f;
    int i = beg;
    for (; i + 7 < end; i += 8) {
        int s0 = psrc[i],     s1 = psrc[i + 1], s2 = psrc[i + 2], s3 = psrc[i + 3];
        int s4 = psrc[i + 4], s5 = psrc[i + 5], s6 = psrc[i + 6], s7 = psrc[i + 7];
        uint4 a0 = ub1t[(size_t)s0 * 2 + h];
        uint4 a1 = ub1t[(size_t)s1 * 2 + h];
        uint4 a2 = ub1t[(size_t)s2 * 2 + h];
        uint4 a3 = ub1t[(size_t)s3 * 2 + h];
        uint4 a4 = ub1t[(size_t)s4 * 2 + h];
        uint4 a5 = ub1t[(size_t)s5 * 2 + h];
        uint4 a6 = ub1t[(size_t)s6 * 2 + h];
        uint4 a7 = ub1t[(size_t)s7 * 2 + h];
        add8(a0, acc); add8(a1, acc); add8(a2, acc); add8(a3, acc);
        add8(a4, acc); add8(a5, acc); add8(a6, acc); add8(a7, acc);
    }
    for (; i < end; i++) add8(ub1t[(size_t)psrc[i] * 2 + h], acc);
    size_t o2 = (size_t)n * 2 + h;
    float z0[8], hrow[8];
    unpack8(z0t[o2], z0);
    if (d2[n] == 0.0f) {   // deg-0: S = z0 - z2
        float z2[8];
        unpack8(z2rt[o2], z2);
#pragma unroll
        for (int j = 0; j < 8; j++) hrow[j] = fmaxf(sb1[h * 8 + j] + z0[j] - z2[j], 0.0f);
    } else {
        float b2v[8];
        unpack8(ub2t[o2], b2v);
        float dn = dis[n], iv = inv[n];
#pragma unroll
        for (int j = 0; j < 8; j++)
            hrow[j] = fmaxf(sb1[h * 8 + j] + z0[j] - dn * acc[j] - iv * b2v[j], 0.0f);
    }
    // exchange halves -> full h16
    float h16[16];
#pragma unroll
    for (int j = 0; j < 8; j++) {
        float other = __shfl_xor(hrow[j], 1);
        h16[h * 8 + j] = hrow[j];
        h16[(1 - h) * 8 + j] = other;
    }
    // w_k = h @ W2[k], this lane's 8 output cols (h*8 .. h*8+7)
    float w0[8], w1[8], w2[8], w3[8];
#pragma unroll
    for (int o = 0; o < 8; o++) { w0[o] = 0.f; w1[o] = 0.f; w2[o] = 0.f; w3[o] = 0.f; }
#pragma unroll
    for (int j = 0; j < 16; j++) {
        float hv = h16[j];
        const float* Wb = sW + j * 16 + h * 8;
#pragma unroll
        for (int o = 0; o < 8; o++) {
            w0[o] += hv * Wb[o];
            w1[o] += hv * Wb[256 + o];
            w2[o] += hv * Wb[512 + o];
            w3[o] += hv * Wb[768 + o];
        }
    }
    float dn = dis[n];
    float s1[8], s2[8], s3[8];
#pragma unroll
    for (int o = 0; o < 8; o++) { s1[o] = dn * w1[o]; s2[o] = dn * w2[o]; s3[o] = dn * w3[o]; }
    w0t[o2]  = pack8(w0);
    uw1t[o2] = pack8(s1);
    uw2t[o2] = pack8(s2);
    w2rt[o2] = pack8(w2);
    uw3t[o2] = pack8(s3);
}

// final2: L = w0 - dis*Sum Uv1[src] - inv*Uv2 (deg-0: w0 - w2r);
// logits = b2 + L (cols 0..9); log_softmax; lane0 writes 8, lane1 writes 2.
__global__ __launch_bounds__(BLK)
void final2_kernel(const int* __restrict__ rowbeg, const int* __restrict__ rowend,
                   const int* __restrict__ psrc, const float* __restrict__ dis,
                   const float* __restrict__ d2, const float* __restrict__ inv,
                   const uint4* __restrict__ uv1t, const uint4* __restrict__ uv2t,
                   const uint4* __restrict__ w0t, const uint4* __restrict__ w2rt,
                   const float* __restrict__ b2, float* __restrict__ out, int N) {
    __shared__ float sb2[16];
    if (threadIdx.x < 16) sb2[threadIdx.x] = (threadIdx.x < 10) ? b2[threadIdx.x] : 0.0f;
    __syncthreads();
    int t = blockIdx.x * blockDim.x + threadIdx.x;
    int n = t >> 1;
    int c = t & 1;
    if (n >= N) return;
    int beg = rowbeg[n];
    int end = rowend[n];
    float acc[8];
#pragma unroll
    for (int j = 0; j < 8; j++) acc[j] = 0.f;
    int i = beg;
    for (; i + 7 < end; i += 8) {
        int s0 = psrc[i],     s1 = psrc[i + 1], s2 = psrc[i + 2], s3 = psrc[i + 3];
        int s4 = psrc[i + 4], s5 = psrc[i + 5], s6 = psrc[i + 6], s7 = psrc[i + 7];
        uint4 a0 = uv1t[(size_t)s0 * 2 + c];
        uint4 a1 = uv1t[(size_t)s1 * 2 + c];
        uint4 a2 = uv1t[(size_t)s2 * 2 + c];
        uint4 a3 = uv1t[(size_t)s3 * 2 + c];
        uint4 a4 = uv1t[(size_t)s4 * 2 + c];
        uint4 a5 = uv1t[(size_t)s5 * 2 + c];
        uint4 a6 = uv1t[(size_t)s6 * 2 + c];
        uint4 a7 = uv1t[(size_t)s7 * 2 + c];
        add8(a0, acc); add8(a1, acc); add8(a2, acc); add8(a3, acc);
        add8(a4, acc); add8(a5, acc); add8(a6, acc); add8(a7, acc);
    }
    for (; i < end; i++) add8(uv1t[(size_t)psrc[i] * 2 + c], acc);
    size_t o2 = (size_t)n * 2 + c;
    float w0[8], L[8];
    unpack8(w0t[o2], w0);
    if (d2[n] == 0.0f) {
        float w2[8];
        unpack8(w2rt[o2], w2);
#pragma unroll
        for (int j = 0; j < 8; j++) L[j] = sb2[c * 8 + j] + w0[j] - w2[j];
    } else {
        float v2[8];
        unpack8(uv2t[o2], v2);
        float dn = dis[n], iv = inv[n];
#pragma unroll
        for (int j = 0; j < 8; j++)
            L[j] = sb2[c * 8 + j] + w0[j] - dn * acc[j] - iv * v2[j];
    }
    int nreal = (c == 0) ? 8 : 2;   // lane1 holds cols 8,9 (+6 pads)
    float m = -3.0e38f;
    for (int j = 0; j < nreal; j++) m = fmaxf(m, L[j]);
    m = fmaxf(m, __shfl_xor(m, 1));
    float s = 0.0f;
    for (int j = 0; j < nreal; j++) s += expf(L[j] - m);
    s += __shfl_xor(s, 1);
    float lse = m + logf(s);
    float* op = out + (size_t)n * 10 + c * 8;
    for (int j = 0; j < nreal; j++) op[j] = L[j] - lse;
}

extern "C" void kernel_launch(void* const* d_in, const int* in_sizes, int n_in,
                              void* d_out, int out_size, void* d_ws, size_t ws_size,
                              hipStream_t stream) {
    const float* x  = (const float*)d_in[0];
    const int*   ei = (const int*)d_in[1];
    const float* W1 = (const float*)d_in[2];
    const float* b1 = (const float*)d_in[3];
    const float* W2 = (const float*)d_in[4];
    const float* b2 = (const float*)d_in[5];
    float* out = (float*)d_out;

    const int N = in_sizes[0] / 32;   // 100000
    const int E = in_sizes[1] / 2;    // 1600000
    const int* src = ei;
    const int* dst = ei + E;

    const int nbuck = (N + 511) / 512;        // 196

    // workspace layout (16B-aligned); all feature tables are N x 32B (2 uint4)
    char* w = (char*)d_ws;
    int*   bfill  = (int*)w;              w += NBUCK_MAX * 4;
    int*   rowbeg = (int*)w;              w += (size_t)(N + 4) * 4;
    int*   rowend = (int*)w;              w += (size_t)(N + 4) * 4;
    float* dis    = (float*)w;            w += (size_t)N * 4;
    float* d2     = (float*)w;            w += (size_t)N * 4;
    float* inv    = (float*)w;            w += (size_t)N * 4;
    int*   tmp    = (int*)w;              w += (size_t)NBUCK_MAX * CAPB * 4;
    int*   psrc   = (int*)w;              w += (size_t)NBUCK_MAX * CAPB * 4;
    uint4* z0t    = (uint4*)w;            w += (size_t)32 * N;
    uint4* uz1t   = (uint4*)w;            w += (size_t)32 * N;
    uint4* uz2t   = (uint4*)w;            w += (size_t)32 * N;
    uint4* uz3t   = (uint4*)w;            w += (size_t)32 * N;
    uint4* z2rt   = (uint4*)w;            w += (size_t)32 * N;
    uint4* ub2t   = (uint4*)w;            w += (size_t)32 * N;
    uint4* ub1t   = (uint4*)w;            w += (size_t)32 * N;
    uint4* w0t    = (uint4*)w;            w += (size_t)32 * N;
    uint4* uw1t   = (uint4*)w;            w += (size_t)32 * N;
    uint4* uw2t   = (uint4*)w;            w += (size_t)32 * N;
    uint4* uw3t   = (uint4*)w;            w += (size_t)32 * N;
    uint4* w2rt   = (uint4*)w;            w += (size_t)32 * N;
    uint4* uv2t   = (uint4*)w;            w += (size_t)32 * N;
    uint4* uv1t   = (uint4*)w;            w += (size_t)32 * N;

    int gN2 = (N * 2 + BLK - 1) / BLK;    // 2 lanes/node kernels
    int gCH = (E + CHUNK - 1) / CHUNK;

    // ---- CSR build ----
    hipMemsetAsync(bfill, 0, NBUCK_MAX * sizeof(int), stream);
    binned_scatter_kernel<<<gCH, BLK, 0, stream>>>(src, dst, bfill, tmp, E, nbuck);
    bucket_place_kernel<<<nbuck, BLKP, 0, stream>>>(bfill, tmp, psrc, rowbeg, rowend,
                                                    dis, d2, inv, N);

    // ---- layer 1 (Clenshaw in 16-feature domain) ----
    zgen_kernel<<<gN2, BLK, 0, stream>>>(x, dis, W1, z0t, uz1t, uz2t, uz3t, z2rt, N);
    // Ub2 = uz2 - 2*d2*Sum uz3[src]
    prop_cl_kernel<false><<<gN2, BLK, 0, stream>>>(rowbeg, rowend, psrc, d2,
                                                   uz3t, uz2t, nullptr, ub2t, N);
    // Ub1 = uz1 - 2*d2*Sum Ub2[src] - uz3
    prop_cl_kernel<true ><<<gN2, BLK, 0, stream>>>(rowbeg, rowend, psrc, d2,
                                                   ub2t, uz1t, uz3t, ub1t, N);
    // h = relu(b1 + z0 - dis*Sum Ub1 - inv*Ub2); w_k = h @ W2[k]
    final1_kernel<<<gN2, BLK, 0, stream>>>(rowbeg, rowend, psrc, dis, d2, inv,
                                           ub1t, ub2t, z0t, z2rt, W2, b1,
                                           w0t, uw1t, uw2t, uw3t, w2rt, N);

    // ---- layer 2 (Clenshaw in 10(->16)-feature domain) ----
    prop_cl_kernel<false><<<gN2, BLK, 0, stream>>>(rowbeg, rowend, psrc, d2,
                                                   uw3t, uw2t, nullptr, uv2t, N);
    prop_cl_kernel<true ><<<gN2, BLK, 0, stream>>>(rowbeg, rowend, psrc, d2,
                                                   uv2t, uw1t, uw3t, uv1t, N);
    final2_kernel<<<gN2, BLK, 0, stream>>>(rowbeg, rowend, psrc, dis, d2, inv,
                                           uv1t, uv2t, w0t, w2rt, b2, out, N);
}

// Round 19
// 248.033 us; speedup vs baseline: 1.1919x; 1.0113x over previous
//
#include <hip/hip_runtime.h>
#include <hip/hip_bf16.h>
#include <math.h>

// ChebyNet: 2-layer ChebConv (K=4), N=100000, E=1600000, F 32->16->10, log_softmax.
//
// R19 = R18 (Clenshaw) + CHUNK 8192->4096: binned_scatter was parallelism-
// starved at 196 blocks (<1 block/CU on 256 CUs, 4 serial LDS passes over
// 8192 edges each). 4096 -> 391 blocks, 28KB LDS (5 blocks/CU capacity).
// R18 recap: z_k = x@W1[k] FIRST, then Clenshaw S = sum_k T_k(L) z_k --
// all six gathers run in the 16-feature domain (32B bf16 rows, 3.2MB tables
// that fit the 4MB/XCD L2). U-space folding: Ub_k = uz_k - 2*d2*Sum
// Ub_{k+1}[src] - Ub_{k+2}; S = z0 - dis*Sum Ub1[src] - inv*Ub2. final1 =
// last gather + relu + w_k=h@W2[k]; final2 = last gather + log_softmax.
// deg-0 exact via raw z2/w2 tables. Build: fixed-capacity buckets,
// src-quartile edge ordering, __launch_bounds__ everywhere.

#define BLK 256
#define BLKP 512
#define NBUCK_MAX 256   // buckets = ceil(N/512); requires N <= 131072
#define CHUNK 4096      // edges per binned_scatter block (R19: was 8192)
#define CAPB 16384      // fixed capacity per bucket region in tmp/psrc
#define PLACE_CAP 10240 // LDS staging capacity in bucket_place (avg bucket 8192)

// ---------- bf16 helpers (storage-only quantization) ----------
__device__ inline unsigned short f32_to_bf16_rne(float f) {
    unsigned int u = __float_as_uint(f);
    unsigned int rounding = 0x7FFFu + ((u >> 16) & 1u);
    return (unsigned short)((u + rounding) >> 16);
}
__device__ inline unsigned int pack_bf16x2(float a, float b) {
    return (unsigned int)f32_to_bf16_rne(a) | ((unsigned int)f32_to_bf16_rne(b) << 16);
}
__device__ inline void unpack8(const uint4 u, float* f) {
    const unsigned int* p = &u.x;
#pragma unroll
    for (int j = 0; j < 4; j++) {
        unsigned int w = p[j];
        f[2 * j]     = __uint_as_float(w << 16);
        f[2 * j + 1] = __uint_as_float(w & 0xFFFF0000u);
    }
}
__device__ inline void add8(const uint4 u, float* acc) {
    const unsigned int* p = &u.x;
#pragma unroll
    for (int j = 0; j < 4; j++) {
        unsigned int w = p[j];
        acc[2 * j]     += __uint_as_float(w << 16);
        acc[2 * j + 1] += __uint_as_float(w & 0xFFFF0000u);
    }
}
__device__ inline uint4 pack8(const float* r) {
    uint4 o;
    o.x = pack_bf16x2(r[0], r[1]);
    o.y = pack_bf16x2(r[2], r[3]);
    o.z = pack_bf16x2(r[4], r[5]);
    o.w = pack_bf16x2(r[6], r[7]);
    return o;
}

// ---------- CSR build (fixed-capacity buckets) ----------
__global__ __launch_bounds__(BLK)
void binned_scatter_kernel(const int* __restrict__ src, const int* __restrict__ dst,
                           int* __restrict__ bfill, int* __restrict__ tmp,
                           int E, int nbuck) {
    __shared__ int cnt[NBUCK_MAX];
    __shared__ int lofs[NBUCK_MAX + 1];
    __shared__ int pos[NBUCK_MAX];
    __shared__ int gbase[NBUCK_MAX];
    __shared__ int stage[CHUNK];
    __shared__ unsigned char bkt[CHUNK];

    int tid = threadIdx.x;
    int e0 = blockIdx.x * CHUNK;
    int nE = min(CHUNK, E - e0);

    for (int b = tid; b < nbuck; b += BLK) { cnt[b] = 0; pos[b] = 0; }
    __syncthreads();

    for (int i = tid; i < nE; i += BLK) {
        int d = dst[e0 + i];
        atomicAdd(&cnt[d >> 9], 1);
    }
    __syncthreads();

    {
        int v = (tid < nbuck) ? cnt[tid] : 0;
        lofs[tid] = v;
        __syncthreads();
        for (int off = 1; off < BLK; off <<= 1) {
            int t = (tid >= off) ? lofs[tid - off] : 0;
            __syncthreads();
            lofs[tid] += t;
            __syncthreads();
        }
        int incl = lofs[tid];
        __syncthreads();
        lofs[tid] = incl - v;
        if (tid == 0) lofs[nbuck] = nE;
        if (tid < nbuck && v > 0)
            gbase[tid] = tid * CAPB + atomicAdd(&bfill[tid], v);
    }
    __syncthreads();

    for (int i = tid; i < nE; i += BLK) {
        int s = src[e0 + i];
        int d = dst[e0 + i];
        int b = d >> 9;
        int slot = lofs[b] + atomicAdd(&pos[b], 1);
        stage[slot] = (s << 9) | (d & 511);
        bkt[slot] = (unsigned char)b;
    }
    __syncthreads();

    for (int i = tid; i < nE; i += BLK) {
        int b = bkt[i];
        tmp[gbase[b] + (i - lofs[b])] = stage[i];
    }
}

// Phase 2: per-bucket degree count/scan -> rowbeg/rowend/dis/d2/inv;
// rank+stage+flush psrc with each node's edges ordered by src quartile.
__global__ __launch_bounds__(BLKP)
void bucket_place_kernel(const int* __restrict__ bfill, const int* __restrict__ tmp,
                         int* __restrict__ psrc, int* __restrict__ rowbeg,
                         int* __restrict__ rowend, float* __restrict__ dis,
                         float* __restrict__ d2, float* __restrict__ inv, int N) {
    __shared__ int cnt4[512 * 4];
    __shared__ int ofs[512];
    __shared__ int fill4[512 * 4];
    __shared__ int stage[PLACE_CAP];

    int b = blockIdx.x;
    int tid = threadIdx.x;
    int n0 = b << 9;
    int nn = min(512, N - n0);
    int S = b * CAPB;
    int tot = bfill[b];

    int t1 = N >> 2, t2 = N >> 1, t3 = t2 + t1;

    for (int i = tid; i < 512 * 4; i += BLKP) { cnt4[i] = 0; fill4[i] = 0; }
    __syncthreads();

    for (int i = tid; i < tot; i += BLKP) {
        int rec = tmp[S + i];
        int nl = rec & 511;
        int s = rec >> 9;
        int q = (s >= t2) ? ((s >= t3) ? 3 : 2) : ((s >= t1) ? 1 : 0);
        atomicAdd(&cnt4[nl * 4 + q], 1);
    }
    __syncthreads();

    int c0 = cnt4[tid * 4 + 0], c1 = cnt4[tid * 4 + 1];
    int c2 = cnt4[tid * 4 + 2], c3 = cnt4[tid * 4 + 3];
    int v = c0 + c1 + c2 + c3;
    cnt4[tid * 4 + 0] = 0;
    cnt4[tid * 4 + 1] = c0;
    cnt4[tid * 4 + 2] = c0 + c1;
    cnt4[tid * 4 + 3] = c0 + c1 + c2;
    ofs[tid] = v;
    __syncthreads();
    for (int off = 1; off < 512; off <<= 1) {
        int t = (tid >= off) ? ofs[tid - off] : 0;
        __syncthreads();
        ofs[tid] += t;
        __syncthreads();
    }
    int excl = ofs[tid] - v;
    __syncthreads();
    ofs[tid] = excl;
    if (tid < nn) {
        int n = n0 + tid;
        rowbeg[n] = S + excl;
        rowend[n] = S + excl + v;
        float fv = (float)v;
        dis[n] = (v > 0) ? rsqrtf(fv) : 0.0f;
        d2[n]  = (v > 0) ? 1.0f / fv : 0.0f;
        inv[n] = (v > 0) ? sqrtf(fv) : 0.0f;
    }
    __syncthreads();

    if (tot <= PLACE_CAP) {
        for (int i = tid; i < tot; i += BLKP) {
            int rec = tmp[S + i];
            int nl = rec & 511;
            int s = rec >> 9;
            int q = (s >= t2) ? ((s >= t3) ? 3 : 2) : ((s >= t1) ? 1 : 0);
            int slot = ofs[nl] + cnt4[nl * 4 + q] + atomicAdd(&fill4[nl * 4 + q], 1);
            stage[slot] = s;
        }
        __syncthreads();
        for (int i = tid; i < tot; i += BLKP) psrc[S + i] = stage[i];
    } else {
        for (int i = tid; i < tot; i += BLKP) {
            int rec = tmp[S + i];
            int nl = rec & 511;
            int s = rec >> 9;
            int q = (s >= t2) ? ((s >= t3) ? 3 : 2) : ((s >= t1) ? 1 : 0);
            int slot = S + ofs[nl] + cnt4[nl * 4 + q] + atomicAdd(&fill4[nl * 4 + q], 1);
            psrc[slot] = s;
        }
    }
}

// z_k = x @ W1[k] for k=0..3; 2 lanes/node (8 outputs each).
// Writes z0 (raw), uz1/uz2/uz3 (dis-scaled), z2r (raw, deg-0 fallback).
__global__ __launch_bounds__(BLK)
void zgen_kernel(const float* __restrict__ x, const float* __restrict__ dis,
                 const float* __restrict__ W1,
                 uint4* __restrict__ z0t, uint4* __restrict__ uz1t,
                 uint4* __restrict__ uz2t, uint4* __restrict__ uz3t,
                 uint4* __restrict__ z2rt, int N) {
    __shared__ float sW[4 * 32 * 16];
    for (int i = threadIdx.x; i < 4 * 32 * 16; i += blockDim.x) sW[i] = W1[i];
    __syncthreads();
    int t = blockIdx.x * blockDim.x + threadIdx.x;
    int n = t >> 1;
    int h = t & 1;
    if (n >= N) return;
    float acc0[8], acc1[8], acc2[8], acc3[8];
#pragma unroll
    for (int j = 0; j < 8; j++) { acc0[j] = 0.f; acc1[j] = 0.f; acc2[j] = 0.f; acc3[j] = 0.f; }
    const float4* x4 = reinterpret_cast<const float4*>(x + (size_t)n * 32);
#pragma unroll
    for (int q = 0; q < 8; q++) {
        float4 a = x4[q];
        float xi[4] = {a.x, a.y, a.z, a.w};
#pragma unroll
        for (int u = 0; u < 4; u++) {
            const float* Wb = sW + (q * 4 + u) * 16 + h * 8;
            float xv = xi[u];
#pragma unroll
            for (int j = 0; j < 8; j++) {
                acc0[j] += xv * Wb[j];
                acc1[j] += xv * Wb[512 + j];
                acc2[j] += xv * Wb[1024 + j];
                acc3[j] += xv * Wb[1536 + j];
            }
        }
    }
    float dn = dis[n];
    float s1[8], s2[8], s3[8];
#pragma unroll
    for (int j = 0; j < 8; j++) { s1[j] = dn * acc1[j]; s2[j] = dn * acc2[j]; s3[j] = dn * acc3[j]; }
    size_t o = (size_t)n * 2 + h;
    z0t[o]  = pack8(acc0);
    uz1t[o] = pack8(s1);
    uz2t[o] = pack8(s2);
    z2rt[o] = pack8(acc2);
    uz3t[o] = pack8(s3);
}

// Clenshaw prop: out = -2*d2[n]*Sum_e vb[src] + addt[n] (- subt[n]). C=2.
template <bool HAVE_SUB>
__global__ __launch_bounds__(BLK)
void prop_cl_kernel(const int* __restrict__ rowbeg, const int* __restrict__ rowend,
                    const int* __restrict__ psrc, const float* __restrict__ d2,
                    const uint4* __restrict__ vb, const uint4* __restrict__ addt,
                    const uint4* __restrict__ subt, uint4* __restrict__ outb, int N) {
    int t = blockIdx.x * blockDim.x + threadIdx.x;
    int n = t >> 1;
    int c = t & 1;
    if (n >= N) return;
    int beg = rowbeg[n];
    int end = rowend[n];
    float acc[8];
#pragma unroll
    for (int j = 0; j < 8; j++) acc[j] = 0.f;
    int i = beg;
    for (; i + 7 < end; i += 8) {
        int s0 = psrc[i],     s1 = psrc[i + 1], s2 = psrc[i + 2], s3 = psrc[i + 3];
        int s4 = psrc[i + 4], s5 = psrc[i + 5], s6 = psrc[i + 6], s7 = psrc[i + 7];
        uint4 a0 = vb[(size_t)s0 * 2 + c];
        uint4 a1 = vb[(size_t)s1 * 2 + c];
        uint4 a2 = vb[(size_t)s2 * 2 + c];
        uint4 a3 = vb[(size_t)s3 * 2 + c];
        uint4 a4 = vb[(size_t)s4 * 2 + c];
        uint4 a5 = vb[(size_t)s5 * 2 + c];
        uint4 a6 = vb[(size_t)s6 * 2 + c];
        uint4 a7 = vb[(size_t)s7 * 2 + c];
        add8(a0, acc); add8(a1, acc); add8(a2, acc); add8(a3, acc);
        add8(a4, acc); add8(a5, acc); add8(a6, acc); add8(a7, acc);
    }
    for (; i < end; i++) add8(vb[(size_t)psrc[i] * 2 + c], acc);
    float f = -2.0f * d2[n];
    float ad[8], r[8];
    unpack8(addt[(size_t)n * 2 + c], ad);
    if (HAVE_SUB) {
        float sb[8];
        unpack8(subt[(size_t)n * 2 + c], sb);
#pragma unroll
        for (int j = 0; j < 8; j++) r[j] = f * acc[j] + ad[j] - sb[j];
    } else {
#pragma unroll
        for (int j = 0; j < 8; j++) r[j] = f * acc[j] + ad[j];
    }
    outb[(size_t)n * 2 + c] = pack8(r);
}

// final1: S = z0 - dis*Sum Ub1[src] - inv*Ub2 (deg-0: z0 - z2r); h = relu(b1+S);
// then w_k = h @ W2[k] (16-padded cols) -> w0 raw, uw1/uw2/uw3 dis-scaled, w2r raw.
__global__ __launch_bounds__(BLK)
void final1_kernel(const int* __restrict__ rowbeg, const int* __restrict__ rowend,
                   const int* __restrict__ psrc, const float* __restrict__ dis,
                   const float* __restrict__ d2, const float* __restrict__ inv,
                   const uint4* __restrict__ ub1t, const uint4* __restrict__ ub2t,
                   const uint4* __restrict__ z0t, const uint4* __restrict__ z2rt,
                   const float* __restrict__ W2, const float* __restrict__ b1,
                   uint4* __restrict__ w0t, uint4* __restrict__ uw1t,
                   uint4* __restrict__ uw2t, uint4* __restrict__ uw3t,
                   uint4* __restrict__ w2rt, int N) {
    __shared__ float sW[4 * 16 * 16];   // W2 padded to 16 cols (zeros beyond col 9)
    __shared__ float sb1[16];
    for (int i = threadIdx.x; i < 4 * 16 * 16; i += blockDim.x) {
        int k = i >> 8, rem = i & 255, j = rem >> 4, o = rem & 15;
        sW[i] = (o < 10) ? W2[k * 160 + j * 10 + o] : 0.0f;
    }
    if (threadIdx.x < 16) sb1[threadIdx.x] = b1[threadIdx.x];
    __syncthreads();
    int t = blockIdx.x * blockDim.x + threadIdx.x;
    int n = t >> 1;
    int h = t & 1;
    if (n >= N) return;
    int beg = rowbeg[n];
    int end = rowend[n];
    float acc[8];
#pragma unroll
    for (int j = 0; j < 8; j++) acc[j] = 0.f;
    int i = beg;
    for (; i + 7 < end; i += 8) {
        int s0 = psrc[i],     s1 = psrc[i + 1], s2 = psrc[i + 2], s3 = psrc[i + 3];
        int s4 = psrc[i + 4], s5 = psrc[i + 5], s6 = psrc[i + 6], s7 = psrc[i + 7];
        uint4 a0 = ub1t[(size_t)s0 * 2 + h];
        uint4 a1 = ub1t[(size_t)s1 * 2 + h];
        uint4 a2 = ub1t[(size_t)s2 * 2 + h];
        uint4 a3 = ub1t[(size_t)s3 * 2 + h];
        uint4 a4 = ub1t[(size_t)s4 * 2 + h];
        uint4 a5 = ub1t[(size_t)s5 * 2 + h];
        uint4 a6 = ub1t[(size_t)s6 * 2 + h];
        uint4 a7 = ub1t[(size_t)s7 * 2 + h];
        add8(a0, acc); add8(a1, acc); add8(a2, acc); add8(a3, acc);
        add8(a4, acc); add8(a5, acc); add8(a6, acc); add8(a7, acc);
    }
    for (; i < end; i++) add8(ub1t[(size_t)psrc[i] * 2 + h], acc);
    size_t o2 = (size_t)n * 2 + h;
    float z0[8], hrow[8];
    unpack8(z0t[o2], z0);
    if (d2[n] == 0.0f) {   // deg-0: S = z0 - z2
        float z2[8];
        unpack8(z2rt[o2], z2);
#pragma unroll
        for (int j = 0; j < 8; j++) hrow[j] = fmaxf(sb1[h * 8 + j] + z0[j] - z2[j], 0.0f);
    } else {
        float b2v[8];
        unpack8(ub2t[o2], b2v);
        float dn = dis[n], iv = inv[n];
#pragma unroll
        for (int j = 0; j < 8; j++)
            hrow[j] = fmaxf(sb1[h * 8 + j] + z0[j] - dn * acc[j] - iv * b2v[j], 0.0f);
    }
    // exchange halves -> full h16
    float h16[16];
#pragma unroll
    for (int j = 0; j < 8; j++) {
        float other = __shfl_xor(hrow[j], 1);
        h16[h * 8 + j] = hrow[j];
        h16[(1 - h) * 8 + j] = other;
    }
    // w_k = h @ W2[k], this lane's 8 output cols (h*8 .. h*8+7)
    float w0[8], w1[8], w2[8], w3[8];
#pragma unroll
    for (int o = 0; o < 8; o++) { w0[o] = 0.f; w1[o] = 0.f; w2[o] = 0.f; w3[o] = 0.f; }
#pragma unroll
    for (int j = 0; j < 16; j++) {
        float hv = h16[j];
        const float* Wb = sW + j * 16 + h * 8;
#pragma unroll
        for (int o = 0; o < 8; o++) {
            w0[o] += hv * Wb[o];
            w1[o] += hv * Wb[256 + o];
            w2[o] += hv * Wb[512 + o];
            w3[o] += hv * Wb[768 + o];
        }
    }
    float dn = dis[n];
    float s1[8], s2[8], s3[8];
#pragma unroll
    for (int o = 0; o < 8; o++) { s1[o] = dn * w1[o]; s2[o] = dn * w2[o]; s3[o] = dn * w3[o]; }
    w0t[o2]  = pack8(w0);
    uw1t[o2] = pack8(s1);
    uw2t[o2] = pack8(s2);
    w2rt[o2] = pack8(w2);
    uw3t[o2] = pack8(s3);
}

// final2: L = w0 - dis*Sum Uv1[src] - inv*Uv2 (deg-0: w0 - w2r);
// logits = b2 + L (cols 0..9); log_softmax; lane0 writes 8, lane1 writes 2.
__global__ __launch_bounds__(BLK)
void final2_kernel(const int* __restrict__ rowbeg, const int* __restrict__ rowend,
                   const int* __restrict__ psrc, const float* __restrict__ dis,
                   const float* __restrict__ d2, const float* __restrict__ inv,
                   const uint4* __restrict__ uv1t, const uint4* __restrict__ uv2t,
                   const uint4* __restrict__ w0t, const uint4* __restrict__ w2rt,
                   const float* __restrict__ b2, float* __restrict__ out, int N) {
    __shared__ float sb2[16];
    if (threadIdx.x < 16) sb2[threadIdx.x] = (threadIdx.x < 10) ? b2[threadIdx.x] : 0.0f;
    __syncthreads();
    int t = blockIdx.x * blockDim.x + threadIdx.x;
    int n = t >> 1;
    int c = t & 1;
    if (n >= N) return;
    int beg = rowbeg[n];
    int end = rowend[n];
    float acc[8];
#pragma unroll
    for (int j = 0; j < 8; j++) acc[j] = 0.f;
    int i = beg;
    for (; i + 7 < end; i += 8) {
        int s0 = psrc[i],     s1 = psrc[i + 1], s2 = psrc[i + 2], s3 = psrc[i + 3];
        int s4 = psrc[i + 4], s5 = psrc[i + 5], s6 = psrc[i + 6], s7 = psrc[i + 7];
        uint4 a0 = uv1t[(size_t)s0 * 2 + c];
        uint4 a1 = uv1t[(size_t)s1 * 2 + c];
        uint4 a2 = uv1t[(size_t)s2 * 2 + c];
        uint4 a3 = uv1t[(size_t)s3 * 2 + c];
        uint4 a4 = uv1t[(size_t)s4 * 2 + c];
        uint4 a5 = uv1t[(size_t)s5 * 2 + c];
        uint4 a6 = uv1t[(size_t)s6 * 2 + c];
        uint4 a7 = uv1t[(size_t)s7 * 2 + c];
        add8(a0, acc); add8(a1, acc); add8(a2, acc); add8(a3, acc);
        add8(a4, acc); add8(a5, acc); add8(a6, acc); add8(a7, acc);
    }
    for (; i < end; i++) add8(uv1t[(size_t)psrc[i] * 2 + c], acc);
    size_t o2 = (size_t)n * 2 + c;
    float w0[8], L[8];
    unpack8(w0t[o2], w0);
    if (d2[n] == 0.0f) {
        float w2[8];
        unpack8(w2rt[o2], w2);
#pragma unroll
        for (int j = 0; j < 8; j++) L[j] = sb2[c * 8 + j] + w0[j] - w2[j];
    } else {
        float v2[8];
        unpack8(uv2t[o2], v2);
        float dn = dis[n], iv = inv[n];
#pragma unroll
        for (int j = 0; j < 8; j++)
            L[j] = sb2[c * 8 + j] + w0[j] - dn * acc[j] - iv * v2[j];
    }
    int nreal = (c == 0) ? 8 : 2;   // lane1 holds cols 8,9 (+6 pads)
    float m = -3.0e38f;
    for (int j = 0; j < nreal; j++) m = fmaxf(m, L[j]);
    m = fmaxf(m, __shfl_xor(m, 1));
    float s = 0.0f;
    for (int j = 0; j < nreal; j++) s += expf(L[j] - m);
    s += __shfl_xor(s, 1);
    float lse = m + logf(s);
    float* op = out + (size_t)n * 10 + c * 8;
    for (int j = 0; j < nreal; j++) op[j] = L[j] - lse;
}

extern "C" void kernel_launch(void* const* d_in, const int* in_sizes, int n_in,
                              void* d_out, int out_size, void* d_ws, size_t ws_size,
                              hipStream_t stream) {
    const float* x  = (const float*)d_in[0];
    const int*   ei = (const int*)d_in[1];
    const float* W1 = (const float*)d_in[2];
    const float* b1 = (const float*)d_in[3];
    const float* W2 = (const float*)d_in[4];
    const float* b2 = (const float*)d_in[5];
    float* out = (float*)d_out;

    const int N = in_sizes[0] / 32;   // 100000
    const int E = in_sizes[1] / 2;    // 1600000
    const int* src = ei;
    const int* dst = ei + E;

    const int nbuck = (N + 511) / 512;        // 196

    // workspace layout (16B-aligned); all feature tables are N x 32B (2 uint4)
    char* w = (char*)d_ws;
    int*   bfill  = (int*)w;              w += NBUCK_MAX * 4;
    int*   rowbeg = (int*)w;              w += (size_t)(N + 4) * 4;
    int*   rowend = (int*)w;              w += (size_t)(N + 4) * 4;
    float* dis    = (float*)w;            w += (size_t)N * 4;
    float* d2     = (float*)w;            w += (size_t)N * 4;
    float* inv    = (float*)w;            w += (size_t)N * 4;
    int*   tmp    = (int*)w;              w += (size_t)NBUCK_MAX * CAPB * 4;
    int*   psrc   = (int*)w;              w += (size_t)NBUCK_MAX * CAPB * 4;
    uint4* z0t    = (uint4*)w;            w += (size_t)32 * N;
    uint4* uz1t   = (uint4*)w;            w += (size_t)32 * N;
    uint4* uz2t   = (uint4*)w;            w += (size_t)32 * N;
    uint4* uz3t   = (uint4*)w;            w += (size_t)32 * N;
    uint4* z2rt   = (uint4*)w;            w += (size_t)32 * N;
    uint4* ub2t   = (uint4*)w;            w += (size_t)32 * N;
    uint4* ub1t   = (uint4*)w;            w += (size_t)32 * N;
    uint4* w0t    = (uint4*)w;            w += (size_t)32 * N;
    uint4* uw1t   = (uint4*)w;            w += (size_t)32 * N;
    uint4* uw2t   = (uint4*)w;            w += (size_t)32 * N;
    uint4* uw3t   = (uint4*)w;            w += (size_t)32 * N;
    uint4* w2rt   = (uint4*)w;            w += (size_t)32 * N;
    uint4* uv2t   = (uint4*)w;            w += (size_t)32 * N;
    uint4* uv1t   = (uint4*)w;            w += (size_t)32 * N;

    int gN2 = (N * 2 + BLK - 1) / BLK;    // 2 lanes/node kernels
    int gCH = (E + CHUNK - 1) / CHUNK;

    // ---- CSR build ----
    hipMemsetAsync(bfill, 0, NBUCK_MAX * sizeof(int), stream);
    binned_scatter_kernel<<<gCH, BLK, 0, stream>>>(src, dst, bfill, tmp, E, nbuck);
    bucket_place_kernel<<<nbuck, BLKP, 0, stream>>>(bfill, tmp, psrc, rowbeg, rowend,
                                                    dis, d2, inv, N);

    // ---- layer 1 (Clenshaw in 16-feature domain) ----
    zgen_kernel<<<gN2, BLK, 0, stream>>>(x, dis, W1, z0t, uz1t, uz2t, uz3t, z2rt, N);
    // Ub2 = uz2 - 2*d2*Sum uz3[src]
    prop_cl_kernel<false><<<gN2, BLK, 0, stream>>>(rowbeg, rowend, psrc, d2,
                                                   uz3t, uz2t, nullptr, ub2t, N);
    // Ub1 = uz1 - 2*d2*Sum Ub2[src] - uz3
    prop_cl_kernel<true ><<<gN2, BLK, 0, stream>>>(rowbeg, rowend, psrc, d2,
                                                   ub2t, uz1t, uz3t, ub1t, N);
    // h = relu(b1 + z0 - dis*Sum Ub1 - inv*Ub2); w_k = h @ W2[k]
    final1_kernel<<<gN2, BLK, 0, stream>>>(rowbeg, rowend, psrc, dis, d2, inv,
                                           ub1t, ub2t, z0t, z2rt, W2, b1,
                                           w0t, uw1t, uw2t, uw3t, w2rt, N);

    // ---- layer 2 (Clenshaw in 10(->16)-feature domain) ----
    prop_cl_kernel<false><<<gN2, BLK, 0, stream>>>(rowbeg, rowend, psrc, d2,
                                                   uw3t, uw2t, nullptr, uv2t, N);
    prop_cl_kernel<true ><<<gN2, BLK, 0, stream>>>(rowbeg, rowend, psrc, d2,
                                                   uv2t, uw1t, uw3t, uv1t, N);
    final2_kernel<<<gN2, BLK, 0, stream>>>(rowbeg, rowend, psrc, dis, d2, inv,
                                           uv1t, uv2t, w0t, w2rt, b2, out, N);
}